// Round 15
// baseline (1042.905 us; speedup 1.0000x reference)
//
#include <hip/hip_runtime.h>
#include <math.h>

#define NB 4
#define BATCH 8
#define NF 128
#define WDIM 512
#define EPS_D 1e-8f

typedef unsigned short ushortT;
typedef __attribute__((ext_vector_type(8))) short short8v;
typedef __attribute__((ext_vector_type(8))) unsigned short ushort8v;
typedef __attribute__((ext_vector_type(4))) float float4v;
typedef __attribute__((ext_vector_type(4))) unsigned int uint4v;
typedef __attribute__((ext_vector_type(2))) unsigned int uint2v;

__device__ inline unsigned short f2bf(float f) {
    unsigned u = __builtin_bit_cast(unsigned, f);
    u = (u + 0x7fffu + ((u >> 16) & 1u)) >> 16;
    return (unsigned short)u;
}
__device__ inline float bf2f(unsigned short h) {
    unsigned u = ((unsigned)h) << 16;
    return __builtin_bit_cast(float, u);
}

// ---------------- style
__global__ void k_style(const float* __restrict__ w,
                        const float* __restrict__ tsw,
                        const float* __restrict__ tsb,
                        float* __restrict__ s) {
    int gid = blockIdx.x * blockDim.x + threadIdx.x;
    if (gid >= NB * BATCH * NF) return;
    int i = gid >> 10;
    int b = (gid >> 7) & 7;
    int o = gid & 127;
    const float cl = 0.044194173824159216f; // 1/sqrt(512)
    const float* wr = w + (i * BATCH + b) * WDIM;
    const float* tr = tsw + (i * NF + o) * WDIM;
    float acc = 0.f;
    for (int k = 0; k < WDIM; ++k) acc += wr[k] * tr[k];
    s[gid] = acc * cl + tsb[i * NF + o];
}

// ---------------- demod (f32 exact)
__global__ void k_demod(const float* __restrict__ conv_w,
                        const float* __restrict__ s,
                        float* __restrict__ d) {
    int bx = blockIdx.x; // l*128 + o
    int l = bx >> 7;
    int o = bx & 127;
    int lane = threadIdx.x;
    const float* wb = conv_w + (size_t)((l * NF + o) * NF) * 9;
    float t0 = 0.f, t1 = 0.f;
    for (int k = 0; k < 9; ++k) {
        float a = wb[lane * 9 + k];        t0 += a * a;
        float c = wb[(lane + 64) * 9 + k]; t1 += c * c;
    }
    const float c2 = 1.0f / 1152.0f;
    int i = l >> 1;
    for (int b = 0; b < BATCH; ++b) {
        float s0 = s[(i * BATCH + b) * NF + lane];
        float s1 = s[(i * BATCH + b) * NF + lane + 64];
        float v = t0 * s0 * s0 + t1 * s1 * s1;
        for (int off = 32; off > 0; off >>= 1) v += __shfl_down(v, off);
        if (lane == 0) d[(l * BATCH + b) * NF + o] = rsqrtf(v * c2 + EPS_D);
    }
}

// ---------------- fragment-major modulated weights
__global__ void k_wmodF(const float* __restrict__ cw, const float* __restrict__ s,
                        ushortT* __restrict__ wm) {
    int idx = blockIdx.x * blockDim.x + threadIdx.x; // 1,179,648
    int lane = idx & 63;
    int mf = (idx >> 6) & 7;
    int kcc = (idx >> 9) & 3;
    int t = (idx >> 11) % 9;
    int r2 = idx / (2048 * 9);
    int b = r2 & 7;
    int l = r2 >> 3;
    if (l >= 8) return;
    const float cscale = 0.029462782549439483f; // 1/sqrt(1152)
    int co = mf * 16 + (lane & 15);
    int kb = kcc * 32 + (lane >> 4) * 8;
    const float* src = cw + (((size_t)l * NF + co) * NF) * 9;
    const float* sr = s + ((l >> 1) * BATCH + b) * NF;
    ushort8v o;
    #pragma unroll
    for (int e = 0; e < 8; ++e) {
        int ci = kb + e;
        o[e] = f2bf(src[(size_t)ci * 9 + t] * cscale * sr[ci]);
    }
    *(ushort8v*)(wm + (size_t)idx * 8) = o;
}

// ---------------- initial constant -> relu -> bf16 NHWC
__global__ void k_prep_init(const float* __restrict__ ic, ushortT* __restrict__ xp,
                            int total) {
    for (int idx = blockIdx.x * blockDim.x + threadIdx.x; idx < total;
         idx += gridDim.x * blockDim.x) {
        int ci = idx & 127;
        int p = (idx >> 7) & 1023;
        float v = ic[ci * 1024 + p];
        xp[idx] = f2bf(v > 0.f ? v : 0.f);
    }
}

// ---------------- 2x bilinear upsample, bf16 NHWC
__global__ void k_up2_bf(const ushortT* __restrict__ in, ushortT* __restrict__ out,
                         int h, int w, int total) {
    int W2 = w * 2, H2 = h * 2;
    for (int gid = blockIdx.x * blockDim.x + threadIdx.x; gid < total;
         gid += gridDim.x * blockDim.x) {
        int cg = gid & 15;
        int t = gid >> 4;
        int ox = t % W2; t /= W2;
        int oy = t % H2; int zb = t / H2;
        int y0 = (oy >> 1) - 1 + (oy & 1);
        float wy0 = (oy & 1) ? 0.75f : 0.25f;
        int x0 = (ox >> 1) - 1 + (ox & 1);
        float wx0 = (ox & 1) ? 0.75f : 0.25f;
        int y1 = min(y0 + 1, h - 1); y0 = max(y0, 0);
        int x1 = min(x0 + 1, w - 1); x0 = max(x0, 0);
        const ushortT* base = in + (size_t)zb * h * w * 128 + cg * 8;
        ushort8v v00 = *(const ushort8v*)(base + (size_t)(y0 * w + x0) * 128);
        ushort8v v01 = *(const ushort8v*)(base + (size_t)(y0 * w + x1) * 128);
        ushort8v v10 = *(const ushort8v*)(base + (size_t)(y1 * w + x0) * 128);
        ushort8v v11 = *(const ushort8v*)(base + (size_t)(y1 * w + x1) * 128);
        float wy1 = 1.f - wy0, wx1 = 1.f - wx0;
        ushort8v o;
        #pragma unroll
        for (int k = 0; k < 8; ++k) {
            float v = wy0 * (wx0 * bf2f(v00[k]) + wx1 * bf2f(v01[k]))
                    + wy1 * (wx0 * bf2f(v10[k]) + wx1 * bf2f(v11[k]));
            o[k] = f2bf(v);
        }
        *(ushort8v*)(out + ((size_t)(zb * H2 + oy) * W2 + ox) * 128 + cg * 8) = o;
    }
}

// ============ conv for r<=128 tiers (R8/R10-verified structure)
template<int NOY>
__global__ __launch_bounds__(256, 3) void k_conv7(
    const ushortT* __restrict__ xp, ushortT* __restrict__ yp,
    const ushortT* __restrict__ wF, const float* __restrict__ d_b,
    const float* __restrict__ nz, const float* __restrict__ bias,
    const float* __restrict__ sn_ptr, const float* __restrict__ s_blk,
    const float* __restrict__ rgbw_i, float* __restrict__ rgbb,
    int H, int W, int b0, int do_rgb)
{
    __shared__ __align__(16) char lb[46080];
    int tid = threadIdx.x;
    int lane = tid & 63;
    int wv = tid >> 6;
    int wm = wv & 1, wn = wv >> 1;
    int lm = lane & 15, lk = lane >> 4;
    int tilesX = W >> 4;
    int tx0 = (blockIdx.x % tilesX) << 4;
    int ty0 = (blockIdx.x / tilesX) << 3;
    int zb = blockIdx.y;
    int b = b0 + zb;

    const char* xbase = (const char*)(xp + (size_t)zb * H * W * 128);
    int offs[6];
    #pragma unroll
    for (int it = 0; it < 6; ++it) {
        int cw = it * 64 + lane;
        int off = -1;
        if (cw < 360) {
            int chunk = wv * 360 + cw;
            int px = chunk >> 3, slot = chunk & 7;
            int hy = px / 18, hx = px - hy * 18;
            int gy = ty0 + hy - 1, gx = tx0 + hx - 1;
            if ((unsigned)gy < (unsigned)H && (unsigned)gx < (unsigned)W)
                off = (gy * W + gx) * 256 + ((slot ^ (px & 7)) << 4);
        }
        offs[it] = off;
    }
    {
        const uint4v zv = {0, 0, 0, 0};
        #pragma unroll
        for (int c = 0; c < 12; ++c) {
            int idx = tid + c * 256;
            if (idx < 2880) *(uint4v*)(lb + idx * 16) = zv;
        }
    }
    __syncthreads();
    #pragma unroll
    for (int it = 0; it < 6; ++it)
        if (offs[it] >= 0)
            __builtin_amdgcn_global_load_lds(
                (const __attribute__((address_space(1))) void*)(xbase + offs[it]),
                (__attribute__((address_space(3))) void*)(lb + wv * 5760 + it * 1024), 16, 0, 0);
    __syncthreads();
    #pragma unroll
    for (int it = 0; it < 6; ++it)
        if (offs[it] >= 0)
            __builtin_amdgcn_global_load_lds(
                (const __attribute__((address_space(1))) void*)(xbase + offs[it] + 128),
                (__attribute__((address_space(3))) void*)(lb + 23040 + wv * 5760 + it * 1024), 16, 0, 0);

    float4v acc[4][4];
    #pragma unroll
    for (int mf = 0; mf < 4; ++mf)
        #pragma unroll
        for (int nf = 0; nf < 4; ++nf)
            acc[mf][nf] = (float4v){0.f, 0.f, 0.f, 0.f};

    const ushortT* wB = wF + (size_t)b * (9 * 4 * 4096);
    for (int cih = 0; cih < 2; ++cih) {
        if (cih) __syncthreads();
        const char* buf = lb + cih * 23040;
        #pragma unroll
        for (int tap = 0; tap < 9; ++tap) {
            const int dy = (tap < 3) ? 0 : (tap < 6 ? 1 : 2);
            const int dx = tap - dy * 3;
            #pragma unroll
            for (int kc = 0; kc < 2; ++kc) {
                const ushortT* ap = wB + ((size_t)(tap * 4 + cih * 2 + kc) << 12)
                                    + wm * 2048 + lane * 8;
                short8v a0 = *(const short8v*)(ap);
                short8v a1 = *(const short8v*)(ap + 512);
                short8v a2 = *(const short8v*)(ap + 1024);
                short8v a3 = *(const short8v*)(ap + 1536);
                #pragma unroll
                for (int nf = 0; nf < 4; ++nf) {
                    int row = nf * 2 + (lm >> 3) + dy;
                    int col = wn * 8 + (lm & 7) + dx;
                    int hp = row * 18 + col;
                    short8v bf = *(const short8v*)(buf + hp * 128
                                 + ((((kc << 2) + lk) ^ (hp & 7)) << 4));
                    acc[0][nf] = __builtin_amdgcn_mfma_f32_16x16x32_bf16(a0, bf, acc[0][nf], 0, 0, 0);
                    acc[1][nf] = __builtin_amdgcn_mfma_f32_16x16x32_bf16(a1, bf, acc[1][nf], 0, 0, 0);
                    acc[2][nf] = __builtin_amdgcn_mfma_f32_16x16x32_bf16(a2, bf, acc[2][nf], 0, 0, 0);
                    acc[3][nf] = __builtin_amdgcn_mfma_f32_16x16x32_bf16(a3, bf, acc[3][nf], 0, 0, 0);
                }
            }
        }
    }
    __syncthreads();

    float sn = sn_ptr[0];
    float nv[4];
    #pragma unroll
    for (int nf = 0; nf < 4; ++nf) {
        int gy = ty0 + nf * 2 + (lm >> 3);
        int gx = tx0 + wn * 8 + (lm & 7);
        nv[nf] = sn * nz[((size_t)b * H + gy) * W + gx];
    }
    const float cl2 = 0.08838834764831845f;

    if (NOY) {
        float rgbs[4] = {0.f, 0.f, 0.f, 0.f};
        #pragma unroll
        for (int mf = 0; mf < 4; ++mf) {
            int co0 = wm * 64 + mf * 16 + lk * 4;
            float4v dd = *(const float4v*)(d_b + b * 128 + co0);
            float4v bb = *(const float4v*)(bias + co0);
            float4v rw = *(const float4v*)(rgbw_i + co0);
            float4v sv = *(const float4v*)(s_blk + b * 128 + co0);
            #pragma unroll
            for (int nf = 0; nf < 4; ++nf)
                #pragma unroll
                for (int e = 0; e < 4; ++e) {
                    float t = acc[mf][nf][e] * dd[e] + nv[nf] + bb[e];
                    t = t > 0.f ? t : 0.2f * t;
                    rgbs[nf] += t * rw[e] * cl2 * sv[e];
                }
        }
        #pragma unroll
        for (int nf = 0; nf < 4; ++nf) {
            float r = rgbs[nf];
            r += __shfl_xor(r, 16, 64);
            r += __shfl_xor(r, 32, 64);
            if (lane < 16) {
                int gy = ty0 + nf * 2 + (lane >> 3);
                int gx = tx0 + wn * 8 + (lane & 7);
                rgbb[((size_t)(wm * BATCH + b) * H + gy) * W + gx] = r;
            }
        }
        return;
    }

    float rgbs[4] = {0.f, 0.f, 0.f, 0.f};
    unsigned pka[4][4][2];
    #pragma unroll
    for (int mf = 0; mf < 4; ++mf) {
        int co0 = wm * 64 + mf * 16 + lk * 4;
        float4v dd = *(const float4v*)(d_b + b * 128 + co0);
        float4v bb = *(const float4v*)(bias + co0);
        float4v cf = {0.f, 0.f, 0.f, 0.f};
        if (do_rgb) {
            float4v rw = *(const float4v*)(rgbw_i + co0);
            float4v sv = *(const float4v*)(s_blk + b * 128 + co0);
            #pragma unroll
            for (int e = 0; e < 4; ++e) cf[e] = rw[e] * cl2 * sv[e];
        }
        #pragma unroll
        for (int nf = 0; nf < 4; ++nf) {
            float v[4];
            #pragma unroll
            for (int e = 0; e < 4; ++e) {
                float t = acc[mf][nf][e] * dd[e] + nv[nf] + bb[e];
                v[e] = t > 0.f ? t : 0.2f * t;
            }
            if (do_rgb)
                rgbs[nf] += v[0] * cf[0] + v[1] * cf[1] + v[2] * cf[2] + v[3] * cf[3];
            pka[mf][nf][0] = (unsigned)f2bf(v[0]) | ((unsigned)f2bf(v[1]) << 16);
            pka[mf][nf][1] = (unsigned)f2bf(v[2]) | ((unsigned)f2bf(v[3]) << 16);
        }
    }
    if (do_rgb) {
        #pragma unroll
        for (int nf = 0; nf < 4; ++nf) {
            float r = rgbs[nf];
            r += __shfl_xor(r, 16, 64);
            r += __shfl_xor(r, 32, 64);
            if (lane < 16) {
                int gy = ty0 + nf * 2 + (lane >> 3);
                int gx = tx0 + wn * 8 + (lane & 7);
                rgbb[((size_t)(wm * BATCH + b) * H + gy) * W + gx] = r;
            }
        }
    }
    char* xb2 = (char*)(yp + (size_t)zb * H * W * 128);
    #pragma unroll
    for (int h = 0; h < 2; ++h) {
        if (wm == h) {
            #pragma unroll
            for (int mf = 0; mf < 4; ++mf) {
                int cb = (mf * 16 + lk * 4) * 2;
                #pragma unroll
                for (int nf = 0; nf < 4; ++nf) {
                    int pxl = (nf * 2 + (lm >> 3)) * 16 + wn * 8 + (lm & 7);
                    int ad = pxl * 128 + (cb ^ ((pxl & 7) << 4));
                    uint2v pk2;
                    pk2[0] = pka[mf][nf][0];
                    pk2[1] = pka[mf][nf][1];
                    *(uint2v*)(lb + ad) = pk2;
                }
            }
        }
        __syncthreads();
        for (int c = tid; c < 1024; c += 256) {
            int pxl = c >> 3, ck = c & 7;
            uint4v v = *(const uint4v*)(lb + pxl * 128 + ((ck << 4) ^ ((pxl & 7) << 4)));
            int gy = ty0 + (pxl >> 4), gx = tx0 + (pxl & 15);
            *(uint4v*)(xb2 + ((size_t)(gy * W + gx)) * 256 + h * 128 + ck * 16) = v;
        }
        if (h == 0) __syncthreads();
    }
}

// ============ MEGA v2: block 3 fused conv(l6)+conv(l7)+ToRGB.
// Double-buffered quarter DMA (issue q+1 before compute q, drain after) +
// j0out split into co-halves so LDS fits: 2*15360 + 23040 = 53760 B.
// j1 accumulates across halves h=0,1 (kcc = 2h+kc). R14 fence discipline kept.
__global__ __launch_bounds__(256, 2) void k_mega(
    const ushortT* __restrict__ up256,  // [g][256][256][128] bf16
    const ushortT* __restrict__ wm6, const ushortT* __restrict__ wm7,
    const float* __restrict__ d6, const float* __restrict__ d7,
    const float* __restrict__ nz6, const float* __restrict__ nz7,
    const float* __restrict__ bias6, const float* __restrict__ bias7,
    const float* __restrict__ sn6p, const float* __restrict__ sn7p,
    const float* __restrict__ s_blk, const float* __restrict__ rgbw_i,
    float* __restrict__ rgbb, int b0)
{
    __shared__ __align__(16) char lb[53760];  // qbuf0 | qbuf1 | j0out-half
    const int QB = 15360, J0 = 30720;
    int tid = threadIdx.x;
    int lane = tid & 63;
    int wv = tid >> 6;
    int wm = wv & 1, wn = wv >> 1;
    int lm = lane & 15, lk = lane >> 4;
    int tx0 = (blockIdx.x & 15) << 4;
    int ty0 = (blockIdx.x >> 4) << 3;
    int zb = blockIdx.y;
    int b = b0 + zb;

    // per-lane j0 output px info for 6 n-frags: p = wn*96 + nf*16 + lm
    int ib[6], prr[6], pcc[6];
    bool pv[6];
    #pragma unroll
    for (int nf = 0; nf < 6; ++nf) {
        int p = wn * 96 + nf * 16 + lm;
        pv[nf] = (p < 180);
        int pc = pv[nf] ? p : 0;
        prr[nf] = pc / 18;
        pcc[nf] = pc - prr[nf] * 18;
        ib[nf] = prr[nf] * 20 + pcc[nf];
    }

    // staging DMA source offsets: chunk c = tid + k*256 (960 chunks of 16B)
    const char* xbase = (const char*)(up256 + (size_t)zb * 256 * 256 * 128);
    int offs[4];
    #pragma unroll
    for (int k = 0; k < 4; ++k) {
        int c = tid + k * 256;
        int off = -1;
        if (c < 960) {
            int ip = c >> 2, d = c & 3;
            int iy = ip / 20, ix = ip - iy * 20;
            int oy = ty0 + iy - 2, ox = tx0 + ix - 2;
            if ((unsigned)oy < 256u && (unsigned)ox < 256u)
                off = (oy * 256 + ox) * 256 + ((d ^ ((ip >> 1) & 3)) << 4);
        }
        offs[k] = off;
    }
    // zero both quarter buffers (border chunks never written by DMA)
    {
        const uint4v zv = {0, 0, 0, 0};
        for (int c = tid; c < 1920; c += 256) *(uint4v*)(lb + c * 16) = zv;
    }
    __syncthreads();

    float4v j0a[4][6];
    #pragma unroll
    for (int mf = 0; mf < 4; ++mf)
        #pragma unroll
        for (int nf = 0; nf < 6; ++nf)
            j0a[mf][nf] = (float4v){0.f, 0.f, 0.f, 0.f};

    const ushortT* wB6 = wm6 + (size_t)b * (9 * 4 * 4096);
    const ushortT* wB7 = wm7 + (size_t)b * (9 * 4 * 4096);

    #define MISSUE(q, buf) do { \
        __builtin_amdgcn_sched_barrier(0); \
        _Pragma("unroll") \
        for (int k = 0; k < 4; ++k) \
            if (offs[k] >= 0) \
                __builtin_amdgcn_global_load_lds( \
                    (const __attribute__((address_space(1))) void*)(xbase + offs[k] + (q) * 64), \
                    (__attribute__((address_space(3))) void*)(lb + (buf) * QB + k * 4096 + wv * 1024), 16, 0, 0); \
        __builtin_amdgcn_sched_barrier(0); \
    } while (0)

    // prologue: stage quarter 0 into buf0, drain, barrier
    MISSUE(0, 0);
    asm volatile("s_waitcnt vmcnt(0)" ::: "memory");
    __builtin_amdgcn_sched_barrier(0);
    __syncthreads();

    for (int q = 0; q < 4; ++q) {
        // issue next quarter into the other buffer (its last readers finished
        // at the barrier closing iteration q-1)
        if (q < 3) MISSUE(q + 1, (q + 1) & 1);
        // ---- j0 MFMA over quarter q (buf q&1) ----
        const char* qb = lb + (q & 1) * QB;
        #pragma unroll
        for (int tap = 0; tap < 9; ++tap) {
            const int dy = (tap < 3) ? 0 : (tap < 6 ? 1 : 2);
            const int dx = tap - dy * 3;
            const ushortT* ap = wB6 + ((size_t)(tap * 4 + q) << 12) + wm * 2048 + lane * 8;
            short8v a0 = *(const short8v*)(ap);
            short8v a1 = *(const short8v*)(ap + 512);
            short8v a2 = *(const short8v*)(ap + 1024);
            short8v a3 = *(const short8v*)(ap + 1536);
            #pragma unroll
            for (int nf = 0; nf < 6; ++nf) {
                int ipx = ib[nf] + dy * 20 + dx;
                short8v bf = *(const short8v*)(qb + ipx * 64
                             + ((lk ^ ((ipx >> 1) & 3)) << 4));
                j0a[0][nf] = __builtin_amdgcn_mfma_f32_16x16x32_bf16(a0, bf, j0a[0][nf], 0, 0, 0);
                j0a[1][nf] = __builtin_amdgcn_mfma_f32_16x16x32_bf16(a1, bf, j0a[1][nf], 0, 0, 0);
                j0a[2][nf] = __builtin_amdgcn_mfma_f32_16x16x32_bf16(a2, bf, j0a[2][nf], 0, 0, 0);
                j0a[3][nf] = __builtin_amdgcn_mfma_f32_16x16x32_bf16(a3, bf, j0a[3][nf], 0, 0, 0);
            }
        }
        // drain next-quarter DMA (flew under the 216 MFMAs above), then barrier
        asm volatile("s_waitcnt vmcnt(0)" ::: "memory");
        __builtin_amdgcn_sched_barrier(0);
        __syncthreads();
    }
    #undef MISSUE

    // ---- j1 accumulators ----
    float4v acc[4][4];
    #pragma unroll
    for (int mf = 0; mf < 4; ++mf)
        #pragma unroll
        for (int nf = 0; nf < 4; ++nf)
            acc[mf][nf] = (float4v){0.f, 0.f, 0.f, 0.f};

    float sn6 = sn6p[0];
    // ---- two co-half rounds: epilogue-write j0out half h, then j1 kcc=2h,2h+1
    #pragma unroll
    for (int h = 0; h < 2; ++h) {
        if (h) __syncthreads();   // h=1: all waves done reading half 0
        if (wm == h) {
            #pragma unroll
            for (int nf = 0; nf < 6; ++nf) {
                if (!pv[nf]) continue;
                int p = wn * 96 + nf * 16 + lm;
                int oy = ty0 + prr[nf] - 1, ox = tx0 + pcc[nf] - 1;
                bool inimg = ((unsigned)oy < 256u) && ((unsigned)ox < 256u);
                float nv = inimg ? sn6 * nz6[((size_t)b * 256 + oy) * 256 + ox] : 0.f;
                #pragma unroll
                for (int mf = 0; mf < 4; ++mf) {
                    int col = mf * 16 + lk * 4;          // local co 0..63
                    uint2v pk2 = {0u, 0u};
                    if (inimg) {
                        float4v dd = *(const float4v*)(d6 + b * 128 + wm * 64 + col);
                        float4v bb = *(const float4v*)(bias6 + wm * 64 + col);
                        float v[4];
                        #pragma unroll
                        for (int e = 0; e < 4; ++e) {
                            float t = j0a[mf][nf][e] * dd[e] + nv + bb[e];
                            v[e] = t > 0.f ? t : 0.2f * t;
                        }
                        pk2[0] = (unsigned)f2bf(v[0]) | ((unsigned)f2bf(v[1]) << 16);
                        pk2[1] = (unsigned)f2bf(v[2]) | ((unsigned)f2bf(v[3]) << 16);
                    }
                    int ad = p * 128 + ((col * 2) ^ ((p & 7) << 4));
                    *(uint2v*)(lb + J0 + ad) = pk2;
                }
            }
        }
        __syncthreads();
        #pragma unroll
        for (int tap = 0; tap < 9; ++tap) {
            const int dy = (tap < 3) ? 0 : (tap < 6 ? 1 : 2);
            const int dx = tap - dy * 3;
            #pragma unroll
            for (int kc = 0; kc < 2; ++kc) {
                const ushortT* ap = wB7 + ((size_t)(tap * 4 + 2 * h + kc) << 12)
                                    + wm * 2048 + lane * 8;
                short8v a0 = *(const short8v*)(ap);
                short8v a1 = *(const short8v*)(ap + 512);
                short8v a2 = *(const short8v*)(ap + 1024);
                short8v a3 = *(const short8v*)(ap + 1536);
                #pragma unroll
                for (int nf = 0; nf < 4; ++nf) {
                    int row = nf * 2 + (lm >> 3) + dy;
                    int col = wn * 8 + (lm & 7) + dx;
                    int hp = row * 18 + col;
                    short8v bf = *(const short8v*)(lb + J0 + hp * 128
                                 + ((kc * 64 + lk * 16) ^ ((hp & 7) << 4)));
                    acc[0][nf] = __builtin_amdgcn_mfma_f32_16x16x32_bf16(a0, bf, acc[0][nf], 0, 0, 0);
                    acc[1][nf] = __builtin_amdgcn_mfma_f32_16x16x32_bf16(a1, bf, acc[1][nf], 0, 0, 0);
                    acc[2][nf] = __builtin_amdgcn_mfma_f32_16x16x32_bf16(a2, bf, acc[2][nf], 0, 0, 0);
                    acc[3][nf] = __builtin_amdgcn_mfma_f32_16x16x32_bf16(a3, bf, acc[3][nf], 0, 0, 0);
                }
            }
        }
    }

    // ---- j1 epilogue: demod + noise + bias + leaky + ToRGB; no y store ----
    float sn7 = sn7p[0];
    float nv7[4];
    #pragma unroll
    for (int nf = 0; nf < 4; ++nf) {
        int gy = ty0 + nf * 2 + (lm >> 3);
        int gx = tx0 + wn * 8 + (lm & 7);
        nv7[nf] = sn7 * nz7[((size_t)b * 256 + gy) * 256 + gx];
    }
    const float cl2 = 0.08838834764831845f;
    float rgbs[4] = {0.f, 0.f, 0.f, 0.f};
    #pragma unroll
    for (int mf = 0; mf < 4; ++mf) {
        int co0 = wm * 64 + mf * 16 + lk * 4;
        float4v dd = *(const float4v*)(d7 + b * 128 + co0);
        float4v bb = *(const float4v*)(bias7 + co0);
        float4v rw = *(const float4v*)(rgbw_i + co0);
        float4v sv = *(const float4v*)(s_blk + b * 128 + co0);
        #pragma unroll
        for (int nf = 0; nf < 4; ++nf)
            #pragma unroll
            for (int e = 0; e < 4; ++e) {
                float t = acc[mf][nf][e] * dd[e] + nv7[nf] + bb[e];
                t = t > 0.f ? t : 0.2f * t;
                rgbs[nf] += t * rw[e] * cl2 * sv[e];
            }
    }
    #pragma unroll
    for (int nf = 0; nf < 4; ++nf) {
        float r = rgbs[nf];
        r += __shfl_xor(r, 16, 64);
        r += __shfl_xor(r, 32, 64);
        if (lane < 16) {
            int gy = ty0 + nf * 2 + (lane >> 3);
            int gx = tx0 + wn * 8 + (lane & 7);
            rgbb[((size_t)(wm * BATCH + b) * 256 + gy) * 256 + gx] = r;
        }
    }
}

// ---------------- bilinear upsample rgb (r->256), sum 2 partial planes
__global__ void k_rgbacc(const float* __restrict__ rgb, float* __restrict__ acc,
                         int r, int beta, int b0, int g) {
    int idx = blockIdx.x * blockDim.x + threadIdx.x;
    if (idx >= g * 256 * 256) return;
    int ox = idx & 255;
    int oy = (idx >> 8) & 255;
    int b = b0 + (idx >> 16);
    float scale = (float)r * (1.0f / 256.0f);
    float fy = (oy + 0.5f) * scale - 0.5f;
    float fx = (ox + 0.5f) * scale - 0.5f;
    int y0 = (int)floorf(fy); float wy = fy - (float)y0;
    int x0 = (int)floorf(fx); float wx = fx - (float)x0;
    int y1 = min(y0 + 1, r - 1); y0 = max(y0, 0);
    int x1 = min(x0 + 1, r - 1); x0 = max(x0, 0);
    const float* p0 = rgb + (size_t)b * r * r;
    const float* p1 = rgb + (size_t)(BATCH + b) * r * r;
    float v00 = p0[y0 * r + x0] + p1[y0 * r + x0];
    float v01 = p0[y0 * r + x1] + p1[y0 * r + x1];
    float v10 = p0[y1 * r + x0] + p1[y1 * r + x0];
    float v11 = p0[y1 * r + x1] + p1[y1 * r + x1];
    float v = (1.f - wy) * ((1.f - wx) * v00 + wx * v01)
            +        wy  * ((1.f - wx) * v10 + wx * v11);
    int oidx = (b << 16) | (oy << 8) | ox;
    acc[oidx] = (beta ? acc[oidx] : 0.f) + v;
}

__global__ void k_final(float* __restrict__ out, int total) {
    int idx = blockIdx.x * blockDim.x + threadIdx.x;
    if (idx < total) out[idx] = out[idx] * 0.5f + 0.5f;
}

extern "C" void kernel_launch(void* const* d_in, const int* in_sizes, int n_in,
                              void* d_out, int out_size, void* d_ws, size_t ws_size,
                              hipStream_t stream) {
    const float* w     = (const float*)d_in[0];
    const float* noise[4] = {(const float*)d_in[1], (const float*)d_in[2],
                             (const float*)d_in[3], (const float*)d_in[4]};
    const float* ic    = (const float*)d_in[5];
    const float* tsw   = (const float*)d_in[6];
    const float* tsb   = (const float*)d_in[7];
    const float* cw    = (const float*)d_in[8];
    const float* snp   = (const float*)d_in[9];
    const float* sbias = (const float*)d_in[10];
    const float* rgbw  = (const float*)d_in[11];

    const size_t WM_BYTES = 8ull * 8 * 9 * 4 * 8 * 64 * 8 * 2; // 18,874,368
    const size_t RGBB = 2ull * BATCH * 65536 * 4;              // 4,194,304
    const size_t FIXED = 16384 + 32768 + RGBB + WM_BYTES;
    const size_t PER_S = 65536ull * 128 * 2;                   // 16,777,216
    int g = 0;
    for (int cand = 8; cand >= 1; cand >>= 1)
        if (ws_size >= FIXED + 2ull * cand * PER_S) { g = cand; break; }
    if (g == 0) return;

    char* ws = (char*)d_ws;
    float* s_all   = (float*)ws;
    float* d_all   = (float*)(ws + 16384);
    float* rgbb    = (float*)(ws + 49152);
    ushortT* wmall = (ushortT*)(ws + 49152 + RGBB);
    ushortT* bufA  = (ushortT*)(ws + FIXED);
    ushortT* bufB  = (ushortT*)(ws + FIXED + (size_t)g * PER_S);
    float* accb    = (float*)d_out;

    k_style<<<64, 64, 0, stream>>>(w, tsw, tsb, s_all);
    k_demod<<<1024, 64, 0, stream>>>(cw, s_all, d_all);
    k_wmodF<<<4608, 256, 0, stream>>>(cw, s_all, wmall);

    #define CONV(T2, SRC, DST, L, R, B0, G, RGB) do {                          \
        dim3 grid(((R) / 16) * ((R) / 8), (G));                                \
        k_conv7<T2><<<grid, 256, 0, stream>>>((SRC), (DST),                    \
            wmall + (size_t)(L) * (8 * 9 * 4 * 4096), d_all + (L) * BATCH * NF,\
            noise[(L) >> 1] + (size_t)((L) & 1) * BATCH * (R) * (R),           \
            sbias + (L) * NF, snp + (L), s_all + ((L) >> 1) * BATCH * NF,      \
            rgbw + ((L) >> 1) * NF, rgbb, (R), (R), (B0), (RGB));              \
    } while (0)

    if (g >= 2) {
        // ---- blocks 0..2 at full batch 8 ----
        ushortT* xb = bufA;
        ushortT* tb = bufB;
        k_prep_init<<<4096, 256, 0, stream>>>(ic, xb, BATCH * 1024 * 128);
        for (int i = 0; i < 3; ++i) {
            int r = 32 << i;
            if (i > 0) {
                int total = BATCH * r * r * 16;
                int blocks = (total + 255) / 256;
                if (blocks > 2048) blocks = 2048;
                k_up2_bf<<<blocks, 256, 0, stream>>>(xb, tb, r / 2, r / 2, total);
                ushortT* t2 = xb; xb = tb; tb = t2;
            }
            CONV(0, xb, tb, i * 2 + 0, r, 0, BATCH, 0);
            { ushortT* t2 = xb; xb = tb; tb = t2; }
            CONV(0, xb, tb, i * 2 + 1, r, 0, BATCH, 1);
            { ushortT* t2 = xb; xb = tb; tb = t2; }
            int tot = BATCH * 256 * 256;
            k_rgbacc<<<(tot + 255) / 256, 256, 0, stream>>>(rgbb, accb, r, i > 0, 0, BATCH);
        }
        // ---- block 3: per g-group {up2 -> mega}; x128 in xb, up256 in tb ----
        for (int b0 = 0; b0 < BATCH; b0 += g) {
            int total = g * 256 * 256 * 16;
            k_up2_bf<<<2048, 256, 0, stream>>>(xb + (size_t)b0 * 2097152, tb,
                                               128, 128, total);
            dim3 mgrid(512, g);
            k_mega<<<mgrid, 256, 0, stream>>>(tb,
                wmall + 6ull * (8 * 9 * 4 * 4096), wmall + 7ull * (8 * 9 * 4 * 4096),
                d_all + 6 * BATCH * NF, d_all + 7 * BATCH * NF,
                noise[3], noise[3] + (size_t)BATCH * 65536,
                sbias + 6 * NF, sbias + 7 * NF, snp + 6, snp + 7,
                s_all + 3 * BATCH * NF, rgbw + 3 * NF, rgbb, b0);
        }
        int tot = BATCH * 256 * 256;
        k_rgbacc<<<(tot + 255) / 256, 256, 0, stream>>>(rgbb, accb, 256, 1, 0, BATCH);
    } else {
        // ---- fallback g==1: per-sample pipeline ----
        for (int b0 = 0; b0 < BATCH; ++b0) {
            ushortT* xb = bufA;
            ushortT* tb = bufB;
            k_prep_init<<<1024, 256, 0, stream>>>(ic, xb, 1024 * 128);
            for (int i = 0; i < NB; ++i) {
                int r = 32 << i;
                if (i > 0) {
                    int total = r * r * 16;
                    int blocks = (total + 255) / 256;
                    if (blocks > 2048) blocks = 2048;
                    k_up2_bf<<<blocks, 256, 0, stream>>>(xb, tb, r / 2, r / 2, total);
                    ushortT* t2 = xb; xb = tb; tb = t2;
                }
                CONV(0, xb, tb, i * 2 + 0, r, b0, 1, 0);
                { ushortT* t2 = xb; xb = tb; tb = t2; }
                if (i < 3) {
                    CONV(0, xb, tb, i * 2 + 1, r, b0, 1, 1);
                    { ushortT* t2 = xb; xb = tb; tb = t2; }
                } else {
                    CONV(1, xb, tb, 7, r, b0, 1, 1);
                }
                int tot = 1 * 256 * 256;
                k_rgbacc<<<(tot + 255) / 256, 256, 0, stream>>>(rgbb, accb, r, i > 0, b0, 1);
            }
        }
    }
    #undef CONV
    k_final<<<(out_size + 255) / 256, 256, 0, stream>>>(accb, out_size);
}

// Round 16
// 919.846 us; speedup vs baseline: 1.1338x; 1.1338x over previous
//
#include <hip/hip_runtime.h>
#include <math.h>

#define NB 4
#define BATCH 8
#define NF 128
#define WDIM 512
#define EPS_D 1e-8f

typedef unsigned short ushortT;
typedef __attribute__((ext_vector_type(8))) short short8v;
typedef __attribute__((ext_vector_type(8))) unsigned short ushort8v;
typedef __attribute__((ext_vector_type(4))) float float4v;
typedef __attribute__((ext_vector_type(4))) unsigned int uint4v;
typedef __attribute__((ext_vector_type(2))) unsigned int uint2v;

__device__ inline unsigned short f2bf(float f) {
    unsigned u = __builtin_bit_cast(unsigned, f);
    u = (u + 0x7fffu + ((u >> 16) & 1u)) >> 16;
    return (unsigned short)u;
}
__device__ inline float bf2f(unsigned short h) {
    unsigned u = ((unsigned)h) << 16;
    return __builtin_bit_cast(float, u);
}

// ---------------- style
__global__ void k_style(const float* __restrict__ w,
                        const float* __restrict__ tsw,
                        const float* __restrict__ tsb,
                        float* __restrict__ s) {
    int gid = blockIdx.x * blockDim.x + threadIdx.x;
    if (gid >= NB * BATCH * NF) return;
    int i = gid >> 10;
    int b = (gid >> 7) & 7;
    int o = gid & 127;
    const float cl = 0.044194173824159216f; // 1/sqrt(512)
    const float* wr = w + (i * BATCH + b) * WDIM;
    const float* tr = tsw + (i * NF + o) * WDIM;
    float acc = 0.f;
    for (int k = 0; k < WDIM; ++k) acc += wr[k] * tr[k];
    s[gid] = acc * cl + tsb[i * NF + o];
}

// ---------------- demod (f32 exact)
__global__ void k_demod(const float* __restrict__ conv_w,
                        const float* __restrict__ s,
                        float* __restrict__ d) {
    int bx = blockIdx.x; // l*128 + o
    int l = bx >> 7;
    int o = bx & 127;
    int lane = threadIdx.x;
    const float* wb = conv_w + (size_t)((l * NF + o) * NF) * 9;
    float t0 = 0.f, t1 = 0.f;
    for (int k = 0; k < 9; ++k) {
        float a = wb[lane * 9 + k];        t0 += a * a;
        float c = wb[(lane + 64) * 9 + k]; t1 += c * c;
    }
    const float c2 = 1.0f / 1152.0f;
    int i = l >> 1;
    for (int b = 0; b < BATCH; ++b) {
        float s0 = s[(i * BATCH + b) * NF + lane];
        float s1 = s[(i * BATCH + b) * NF + lane + 64];
        float v = t0 * s0 * s0 + t1 * s1 * s1;
        for (int off = 32; off > 0; off >>= 1) v += __shfl_down(v, off);
        if (lane == 0) d[(l * BATCH + b) * NF + o] = rsqrtf(v * c2 + EPS_D);
    }
}

// ---------------- fragment-major modulated weights
__global__ void k_wmodF(const float* __restrict__ cw, const float* __restrict__ s,
                        ushortT* __restrict__ wm) {
    int idx = blockIdx.x * blockDim.x + threadIdx.x; // 1,179,648
    int lane = idx & 63;
    int mf = (idx >> 6) & 7;
    int kcc = (idx >> 9) & 3;
    int t = (idx >> 11) % 9;
    int r2 = idx / (2048 * 9);
    int b = r2 & 7;
    int l = r2 >> 3;
    if (l >= 8) return;
    const float cscale = 0.029462782549439483f; // 1/sqrt(1152)
    int co = mf * 16 + (lane & 15);
    int kb = kcc * 32 + (lane >> 4) * 8;
    const float* src = cw + (((size_t)l * NF + co) * NF) * 9;
    const float* sr = s + ((l >> 1) * BATCH + b) * NF;
    ushort8v o;
    #pragma unroll
    for (int e = 0; e < 8; ++e) {
        int ci = kb + e;
        o[e] = f2bf(src[(size_t)ci * 9 + t] * cscale * sr[ci]);
    }
    *(ushort8v*)(wm + (size_t)idx * 8) = o;
}

// ---------------- initial constant -> relu -> bf16 NHWC
__global__ void k_prep_init(const float* __restrict__ ic, ushortT* __restrict__ xp,
                            int total) {
    for (int idx = blockIdx.x * blockDim.x + threadIdx.x; idx < total;
         idx += gridDim.x * blockDim.x) {
        int ci = idx & 127;
        int p = (idx >> 7) & 1023;
        float v = ic[ci * 1024 + p];
        xp[idx] = f2bf(v > 0.f ? v : 0.f);
    }
}

// ---------------- 2x bilinear upsample, bf16 NHWC
__global__ void k_up2_bf(const ushortT* __restrict__ in, ushortT* __restrict__ out,
                         int h, int w, int total) {
    int W2 = w * 2, H2 = h * 2;
    for (int gid = blockIdx.x * blockDim.x + threadIdx.x; gid < total;
         gid += gridDim.x * blockDim.x) {
        int cg = gid & 15;
        int t = gid >> 4;
        int ox = t % W2; t /= W2;
        int oy = t % H2; int zb = t / H2;
        int y0 = (oy >> 1) - 1 + (oy & 1);
        float wy0 = (oy & 1) ? 0.75f : 0.25f;
        int x0 = (ox >> 1) - 1 + (ox & 1);
        float wx0 = (ox & 1) ? 0.75f : 0.25f;
        int y1 = min(y0 + 1, h - 1); y0 = max(y0, 0);
        int x1 = min(x0 + 1, w - 1); x0 = max(x0, 0);
        const ushortT* base = in + (size_t)zb * h * w * 128 + cg * 8;
        ushort8v v00 = *(const ushort8v*)(base + (size_t)(y0 * w + x0) * 128);
        ushort8v v01 = *(const ushort8v*)(base + (size_t)(y0 * w + x1) * 128);
        ushort8v v10 = *(const ushort8v*)(base + (size_t)(y1 * w + x0) * 128);
        ushort8v v11 = *(const ushort8v*)(base + (size_t)(y1 * w + x1) * 128);
        float wy1 = 1.f - wy0, wx1 = 1.f - wx0;
        ushort8v o;
        #pragma unroll
        for (int k = 0; k < 8; ++k) {
            float v = wy0 * (wx0 * bf2f(v00[k]) + wx1 * bf2f(v01[k]))
                    + wy1 * (wx0 * bf2f(v10[k]) + wx1 * bf2f(v11[k]));
            o[k] = f2bf(v);
        }
        *(ushort8v*)(out + ((size_t)(zb * H2 + oy) * W2 + ox) * 128 + cg * 8) = o;
    }
}

// ============ conv for r<=128 tiers (R8/R10-verified structure)
template<int NOY>
__global__ __launch_bounds__(256, 3) void k_conv7(
    const ushortT* __restrict__ xp, ushortT* __restrict__ yp,
    const ushortT* __restrict__ wF, const float* __restrict__ d_b,
    const float* __restrict__ nz, const float* __restrict__ bias,
    const float* __restrict__ sn_ptr, const float* __restrict__ s_blk,
    const float* __restrict__ rgbw_i, float* __restrict__ rgbb,
    int H, int W, int b0, int do_rgb)
{
    __shared__ __align__(16) char lb[46080];
    int tid = threadIdx.x;
    int lane = tid & 63;
    int wv = tid >> 6;
    int wm = wv & 1, wn = wv >> 1;
    int lm = lane & 15, lk = lane >> 4;
    int tilesX = W >> 4;
    int tx0 = (blockIdx.x % tilesX) << 4;
    int ty0 = (blockIdx.x / tilesX) << 3;
    int zb = blockIdx.y;
    int b = b0 + zb;

    const char* xbase = (const char*)(xp + (size_t)zb * H * W * 128);
    int offs[6];
    #pragma unroll
    for (int it = 0; it < 6; ++it) {
        int cw = it * 64 + lane;
        int off = -1;
        if (cw < 360) {
            int chunk = wv * 360 + cw;
            int px = chunk >> 3, slot = chunk & 7;
            int hy = px / 18, hx = px - hy * 18;
            int gy = ty0 + hy - 1, gx = tx0 + hx - 1;
            if ((unsigned)gy < (unsigned)H && (unsigned)gx < (unsigned)W)
                off = (gy * W + gx) * 256 + ((slot ^ (px & 7)) << 4);
        }
        offs[it] = off;
    }
    {
        const uint4v zv = {0, 0, 0, 0};
        #pragma unroll
        for (int c = 0; c < 12; ++c) {
            int idx = tid + c * 256;
            if (idx < 2880) *(uint4v*)(lb + idx * 16) = zv;
        }
    }
    __syncthreads();
    #pragma unroll
    for (int it = 0; it < 6; ++it)
        if (offs[it] >= 0)
            __builtin_amdgcn_global_load_lds(
                (const __attribute__((address_space(1))) void*)(xbase + offs[it]),
                (__attribute__((address_space(3))) void*)(lb + wv * 5760 + it * 1024), 16, 0, 0);
    __syncthreads();
    #pragma unroll
    for (int it = 0; it < 6; ++it)
        if (offs[it] >= 0)
            __builtin_amdgcn_global_load_lds(
                (const __attribute__((address_space(1))) void*)(xbase + offs[it] + 128),
                (__attribute__((address_space(3))) void*)(lb + 23040 + wv * 5760 + it * 1024), 16, 0, 0);

    float4v acc[4][4];
    #pragma unroll
    for (int mf = 0; mf < 4; ++mf)
        #pragma unroll
        for (int nf = 0; nf < 4; ++nf)
            acc[mf][nf] = (float4v){0.f, 0.f, 0.f, 0.f};

    const ushortT* wB = wF + (size_t)b * (9 * 4 * 4096);
    for (int cih = 0; cih < 2; ++cih) {
        if (cih) __syncthreads();
        const char* buf = lb + cih * 23040;
        #pragma unroll
        for (int tap = 0; tap < 9; ++tap) {
            const int dy = (tap < 3) ? 0 : (tap < 6 ? 1 : 2);
            const int dx = tap - dy * 3;
            #pragma unroll
            for (int kc = 0; kc < 2; ++kc) {
                const ushortT* ap = wB + ((size_t)(tap * 4 + cih * 2 + kc) << 12)
                                    + wm * 2048 + lane * 8;
                short8v a0 = *(const short8v*)(ap);
                short8v a1 = *(const short8v*)(ap + 512);
                short8v a2 = *(const short8v*)(ap + 1024);
                short8v a3 = *(const short8v*)(ap + 1536);
                #pragma unroll
                for (int nf = 0; nf < 4; ++nf) {
                    int row = nf * 2 + (lm >> 3) + dy;
                    int col = wn * 8 + (lm & 7) + dx;
                    int hp = row * 18 + col;
                    short8v bf = *(const short8v*)(buf + hp * 128
                                 + ((((kc << 2) + lk) ^ (hp & 7)) << 4));
                    acc[0][nf] = __builtin_amdgcn_mfma_f32_16x16x32_bf16(a0, bf, acc[0][nf], 0, 0, 0);
                    acc[1][nf] = __builtin_amdgcn_mfma_f32_16x16x32_bf16(a1, bf, acc[1][nf], 0, 0, 0);
                    acc[2][nf] = __builtin_amdgcn_mfma_f32_16x16x32_bf16(a2, bf, acc[2][nf], 0, 0, 0);
                    acc[3][nf] = __builtin_amdgcn_mfma_f32_16x16x32_bf16(a3, bf, acc[3][nf], 0, 0, 0);
                }
            }
        }
    }
    __syncthreads();

    float sn = sn_ptr[0];
    float nv[4];
    #pragma unroll
    for (int nf = 0; nf < 4; ++nf) {
        int gy = ty0 + nf * 2 + (lm >> 3);
        int gx = tx0 + wn * 8 + (lm & 7);
        nv[nf] = sn * nz[((size_t)b * H + gy) * W + gx];
    }
    const float cl2 = 0.08838834764831845f;

    if (NOY) {
        float rgbs[4] = {0.f, 0.f, 0.f, 0.f};
        #pragma unroll
        for (int mf = 0; mf < 4; ++mf) {
            int co0 = wm * 64 + mf * 16 + lk * 4;
            float4v dd = *(const float4v*)(d_b + b * 128 + co0);
            float4v bb = *(const float4v*)(bias + co0);
            float4v rw = *(const float4v*)(rgbw_i + co0);
            float4v sv = *(const float4v*)(s_blk + b * 128 + co0);
            #pragma unroll
            for (int nf = 0; nf < 4; ++nf)
                #pragma unroll
                for (int e = 0; e < 4; ++e) {
                    float t = acc[mf][nf][e] * dd[e] + nv[nf] + bb[e];
                    t = t > 0.f ? t : 0.2f * t;
                    rgbs[nf] += t * rw[e] * cl2 * sv[e];
                }
        }
        #pragma unroll
        for (int nf = 0; nf < 4; ++nf) {
            float r = rgbs[nf];
            r += __shfl_xor(r, 16, 64);
            r += __shfl_xor(r, 32, 64);
            if (lane < 16) {
                int gy = ty0 + nf * 2 + (lane >> 3);
                int gx = tx0 + wn * 8 + (lane & 7);
                rgbb[((size_t)(wm * BATCH + b) * H + gy) * W + gx] = r;
            }
        }
        return;
    }

    float rgbs[4] = {0.f, 0.f, 0.f, 0.f};
    unsigned pka[4][4][2];
    #pragma unroll
    for (int mf = 0; mf < 4; ++mf) {
        int co0 = wm * 64 + mf * 16 + lk * 4;
        float4v dd = *(const float4v*)(d_b + b * 128 + co0);
        float4v bb = *(const float4v*)(bias + co0);
        float4v cf = {0.f, 0.f, 0.f, 0.f};
        if (do_rgb) {
            float4v rw = *(const float4v*)(rgbw_i + co0);
            float4v sv = *(const float4v*)(s_blk + b * 128 + co0);
            #pragma unroll
            for (int e = 0; e < 4; ++e) cf[e] = rw[e] * cl2 * sv[e];
        }
        #pragma unroll
        for (int nf = 0; nf < 4; ++nf) {
            float v[4];
            #pragma unroll
            for (int e = 0; e < 4; ++e) {
                float t = acc[mf][nf][e] * dd[e] + nv[nf] + bb[e];
                v[e] = t > 0.f ? t : 0.2f * t;
            }
            if (do_rgb)
                rgbs[nf] += v[0] * cf[0] + v[1] * cf[1] + v[2] * cf[2] + v[3] * cf[3];
            pka[mf][nf][0] = (unsigned)f2bf(v[0]) | ((unsigned)f2bf(v[1]) << 16);
            pka[mf][nf][1] = (unsigned)f2bf(v[2]) | ((unsigned)f2bf(v[3]) << 16);
        }
    }
    if (do_rgb) {
        #pragma unroll
        for (int nf = 0; nf < 4; ++nf) {
            float r = rgbs[nf];
            r += __shfl_xor(r, 16, 64);
            r += __shfl_xor(r, 32, 64);
            if (lane < 16) {
                int gy = ty0 + nf * 2 + (lane >> 3);
                int gx = tx0 + wn * 8 + (lane & 7);
                rgbb[((size_t)(wm * BATCH + b) * H + gy) * W + gx] = r;
            }
        }
    }
    char* xb2 = (char*)(yp + (size_t)zb * H * W * 128);
    #pragma unroll
    for (int h = 0; h < 2; ++h) {
        if (wm == h) {
            #pragma unroll
            for (int mf = 0; mf < 4; ++mf) {
                int cb = (mf * 16 + lk * 4) * 2;
                #pragma unroll
                for (int nf = 0; nf < 4; ++nf) {
                    int pxl = (nf * 2 + (lm >> 3)) * 16 + wn * 8 + (lm & 7);
                    int ad = pxl * 128 + (cb ^ ((pxl & 7) << 4));
                    uint2v pk2;
                    pk2[0] = pka[mf][nf][0];
                    pk2[1] = pka[mf][nf][1];
                    *(uint2v*)(lb + ad) = pk2;
                }
            }
        }
        __syncthreads();
        for (int c = tid; c < 1024; c += 256) {
            int pxl = c >> 3, ck = c & 7;
            uint4v v = *(const uint4v*)(lb + pxl * 128 + ((ck << 4) ^ ((pxl & 7) << 4)));
            int gy = ty0 + (pxl >> 4), gx = tx0 + (pxl & 15);
            *(uint4v*)(xb2 + ((size_t)(gy * W + gx)) * 256 + h * 128 + ck * 16) = v;
        }
        if (h == 0) __syncthreads();
    }
}

// ============ MEGA v3: block 3 fused conv(l6)+conv(l7)+ToRGB.
// R14 structure (sequential j0a -> j0out -> acc: NO register overlap) +
// pipelined double-buffered quarter DMA. Quarter buffers [0,30720) are
// temporally disjoint from j0out [0,46080) (quarters die at the barrier
// closing q=3), so they SHARE LDS: total 46080 B.
__global__ __launch_bounds__(256, 2) void k_mega(
    const ushortT* __restrict__ up256,  // [g][256][256][128] bf16
    const ushortT* __restrict__ wm6, const ushortT* __restrict__ wm7,
    const float* __restrict__ d6, const float* __restrict__ d7,
    const float* __restrict__ nz6, const float* __restrict__ nz7,
    const float* __restrict__ bias6, const float* __restrict__ bias7,
    const float* __restrict__ sn6p, const float* __restrict__ sn7p,
    const float* __restrict__ s_blk, const float* __restrict__ rgbw_i,
    float* __restrict__ rgbb, int b0)
{
    __shared__ __align__(16) char lb[46080];  // qbuf0|qbuf1 (phase1) / j0out (phase2)
    const int QB = 15360;
    int tid = threadIdx.x;
    int lane = tid & 63;
    int wv = tid >> 6;
    int wm = wv & 1, wn = wv >> 1;
    int lm = lane & 15, lk = lane >> 4;
    int tx0 = (blockIdx.x & 15) << 4;
    int ty0 = (blockIdx.x >> 4) << 3;
    int zb = blockIdx.y;
    int b = b0 + zb;

    // per-lane j0 output px info for 6 n-frags: p = wn*96 + nf*16 + lm
    int ib[6], prr[6], pcc[6];
    bool pv[6];
    #pragma unroll
    for (int nf = 0; nf < 6; ++nf) {
        int p = wn * 96 + nf * 16 + lm;
        pv[nf] = (p < 180);
        int pc = pv[nf] ? p : 0;
        prr[nf] = pc / 18;
        pcc[nf] = pc - prr[nf] * 18;
        ib[nf] = prr[nf] * 20 + pcc[nf];
    }

    // staging DMA source offsets: chunk c = tid + k*256 (960 chunks of 16B)
    const char* xbase = (const char*)(up256 + (size_t)zb * 256 * 256 * 128);
    int offs[4];
    #pragma unroll
    for (int k = 0; k < 4; ++k) {
        int c = tid + k * 256;
        int off = -1;
        if (c < 960) {
            int ip = c >> 2, d = c & 3;
            int iy = ip / 20, ix = ip - iy * 20;
            int oy = ty0 + iy - 2, ox = tx0 + ix - 2;
            if ((unsigned)oy < 256u && (unsigned)ox < 256u)
                off = (oy * 256 + ox) * 256 + ((d ^ ((ip >> 1) & 3)) << 4);
        }
        offs[k] = off;
    }
    // zero both quarter buffers (border chunks never written by DMA)
    {
        const uint4v zv = {0, 0, 0, 0};
        for (int c = tid; c < 1920; c += 256) *(uint4v*)(lb + c * 16) = zv;
    }
    __syncthreads();

    float4v j0a[4][6];
    #pragma unroll
    for (int mf = 0; mf < 4; ++mf)
        #pragma unroll
        for (int nf = 0; nf < 6; ++nf)
            j0a[mf][nf] = (float4v){0.f, 0.f, 0.f, 0.f};

    const ushortT* wB6 = wm6 + (size_t)b * (9 * 4 * 4096);
    const ushortT* wB7 = wm7 + (size_t)b * (9 * 4 * 4096);

    #define MISSUE(q, buf) do { \
        __builtin_amdgcn_sched_barrier(0); \
        _Pragma("unroll") \
        for (int k = 0; k < 4; ++k) \
            if (offs[k] >= 0) \
                __builtin_amdgcn_global_load_lds( \
                    (const __attribute__((address_space(1))) void*)(xbase + offs[k] + (q) * 64), \
                    (__attribute__((address_space(3))) void*)(lb + (buf) * QB + k * 4096 + wv * 1024), 16, 0, 0); \
        __builtin_amdgcn_sched_barrier(0); \
    } while (0)

    // prologue: stage quarter 0 into buf0, drain, barrier
    MISSUE(0, 0);
    asm volatile("s_waitcnt vmcnt(0)" ::: "memory");
    __builtin_amdgcn_sched_barrier(0);
    __syncthreads();

    for (int q = 0; q < 4; ++q) {
        // issue next quarter into the other buffer (its previous readers all
        // finished at the barrier that closed iteration q-1)
        if (q < 3) MISSUE(q + 1, (q + 1) & 1);
        // ---- j0 MFMA over quarter q (buf q&1); DMA flies under these ----
        const char* qb = lb + (q & 1) * QB;
        #pragma unroll
        for (int tap = 0; tap < 9; ++tap) {
            const int dy = (tap < 3) ? 0 : (tap < 6 ? 1 : 2);
            const int dx = tap - dy * 3;
            const ushortT* ap = wB6 + ((size_t)(tap * 4 + q) << 12) + wm * 2048 + lane * 8;
            short8v a0 = *(const short8v*)(ap);
            short8v a1 = *(const short8v*)(ap + 512);
            short8v a2 = *(const short8v*)(ap + 1024);
            short8v a3 = *(const short8v*)(ap + 1536);
            #pragma unroll
            for (int nf = 0; nf < 6; ++nf) {
                int ipx = ib[nf] + dy * 20 + dx;
                short8v bf = *(const short8v*)(qb + ipx * 64
                             + ((lk ^ ((ipx >> 1) & 3)) << 4));
                j0a[0][nf] = __builtin_amdgcn_mfma_f32_16x16x32_bf16(a0, bf, j0a[0][nf], 0, 0, 0);
                j0a[1][nf] = __builtin_amdgcn_mfma_f32_16x16x32_bf16(a1, bf, j0a[1][nf], 0, 0, 0);
                j0a[2][nf] = __builtin_amdgcn_mfma_f32_16x16x32_bf16(a2, bf, j0a[2][nf], 0, 0, 0);
                j0a[3][nf] = __builtin_amdgcn_mfma_f32_16x16x32_bf16(a3, bf, j0a[3][nf], 0, 0, 0);
            }
        }
        // drain the in-flight next-quarter DMA, then barrier
        asm volatile("s_waitcnt vmcnt(0)" ::: "memory");
        __builtin_amdgcn_sched_barrier(0);
        __syncthreads();
    }
    #undef MISSUE
    // quarter buffers dead; lb[0,46080) becomes j0out

    // ---- j0 epilogue -> j0out LDS (swizzled 256B/px, zero outside image) ----
    {
        float sn6 = sn6p[0];
        #pragma unroll
        for (int nf = 0; nf < 6; ++nf) {
            if (!pv[nf]) continue;
            int p = wn * 96 + nf * 16 + lm;
            int oy = ty0 + prr[nf] - 1, ox = tx0 + pcc[nf] - 1;
            bool inimg = ((unsigned)oy < 256u) && ((unsigned)ox < 256u);
            float nv = inimg ? sn6 * nz6[((size_t)b * 256 + oy) * 256 + ox] : 0.f;
            #pragma unroll
            for (int mf = 0; mf < 4; ++mf) {
                int co0 = wm * 64 + mf * 16 + lk * 4;
                uint2v pk2 = {0u, 0u};
                if (inimg) {
                    float4v dd = *(const float4v*)(d6 + b * 128 + co0);
                    float4v bb = *(const float4v*)(bias6 + co0);
                    float v[4];
                    #pragma unroll
                    for (int e = 0; e < 4; ++e) {
                        float t = j0a[mf][nf][e] * dd[e] + nv + bb[e];
                        v[e] = t > 0.f ? t : 0.2f * t;
                    }
                    pk2[0] = (unsigned)f2bf(v[0]) | ((unsigned)f2bf(v[1]) << 16);
                    pk2[1] = (unsigned)f2bf(v[2]) | ((unsigned)f2bf(v[3]) << 16);
                }
                int ad = p * 256 + ((co0 * 2) ^ ((p & 7) << 4));
                *(uint2v*)(lb + ad) = pk2;
            }
        }
    }
    __syncthreads();

    // ---- j1 conv (layer 7) reading j0out; fused ToRGB; no y store ----
    float4v acc[4][4];
    #pragma unroll
    for (int mf = 0; mf < 4; ++mf)
        #pragma unroll
        for (int nf = 0; nf < 4; ++nf)
            acc[mf][nf] = (float4v){0.f, 0.f, 0.f, 0.f};

    #pragma unroll
    for (int tap = 0; tap < 9; ++tap) {
        const int dy = (tap < 3) ? 0 : (tap < 6 ? 1 : 2);
        const int dx = tap - dy * 3;
        #pragma unroll
        for (int kcc = 0; kcc < 4; ++kcc) {
            const ushortT* ap = wB7 + ((size_t)(tap * 4 + kcc) << 12) + wm * 2048 + lane * 8;
            short8v a0 = *(const short8v*)(ap);
            short8v a1 = *(const short8v*)(ap + 512);
            short8v a2 = *(const short8v*)(ap + 1024);
            short8v a3 = *(const short8v*)(ap + 1536);
            #pragma unroll
            for (int nf = 0; nf < 4; ++nf) {
                int row = nf * 2 + (lm >> 3) + dy;
                int col = wn * 8 + (lm & 7) + dx;
                int hp = row * 18 + col;
                short8v bf = *(const short8v*)(lb + hp * 256
                             + ((kcc * 64 + lk * 16) ^ ((hp & 7) << 4)));
                acc[0][nf] = __builtin_amdgcn_mfma_f32_16x16x32_bf16(a0, bf, acc[0][nf], 0, 0, 0);
                acc[1][nf] = __builtin_amdgcn_mfma_f32_16x16x32_bf16(a1, bf, acc[1][nf], 0, 0, 0);
                acc[2][nf] = __builtin_amdgcn_mfma_f32_16x16x32_bf16(a2, bf, acc[2][nf], 0, 0, 0);
                acc[3][nf] = __builtin_amdgcn_mfma_f32_16x16x32_bf16(a3, bf, acc[3][nf], 0, 0, 0);
            }
        }
    }

    float sn7 = sn7p[0];
    float nv7[4];
    #pragma unroll
    for (int nf = 0; nf < 4; ++nf) {
        int gy = ty0 + nf * 2 + (lm >> 3);
        int gx = tx0 + wn * 8 + (lm & 7);
        nv7[nf] = sn7 * nz7[((size_t)b * 256 + gy) * 256 + gx];
    }
    const float cl2 = 0.08838834764831845f;
    float rgbs[4] = {0.f, 0.f, 0.f, 0.f};
    #pragma unroll
    for (int mf = 0; mf < 4; ++mf) {
        int co0 = wm * 64 + mf * 16 + lk * 4;
        float4v dd = *(const float4v*)(d7 + b * 128 + co0);
        float4v bb = *(const float4v*)(bias7 + co0);
        float4v rw = *(const float4v*)(rgbw_i + co0);
        float4v sv = *(const float4v*)(s_blk + b * 128 + co0);
        #pragma unroll
        for (int nf = 0; nf < 4; ++nf)
            #pragma unroll
            for (int e = 0; e < 4; ++e) {
                float t = acc[mf][nf][e] * dd[e] + nv7[nf] + bb[e];
                t = t > 0.f ? t : 0.2f * t;
                rgbs[nf] += t * rw[e] * cl2 * sv[e];
            }
    }
    #pragma unroll
    for (int nf = 0; nf < 4; ++nf) {
        float r = rgbs[nf];
        r += __shfl_xor(r, 16, 64);
        r += __shfl_xor(r, 32, 64);
        if (lane < 16) {
            int gy = ty0 + nf * 2 + (lane >> 3);
            int gx = tx0 + wn * 8 + (lane & 7);
            rgbb[((size_t)(wm * BATCH + b) * 256 + gy) * 256 + gx] = r;
        }
    }
}

// ---------------- bilinear upsample rgb (r->256), sum 2 partial planes
__global__ void k_rgbacc(const float* __restrict__ rgb, float* __restrict__ acc,
                         int r, int beta, int b0, int g) {
    int idx = blockIdx.x * blockDim.x + threadIdx.x;
    if (idx >= g * 256 * 256) return;
    int ox = idx & 255;
    int oy = (idx >> 8) & 255;
    int b = b0 + (idx >> 16);
    float scale = (float)r * (1.0f / 256.0f);
    float fy = (oy + 0.5f) * scale - 0.5f;
    float fx = (ox + 0.5f) * scale - 0.5f;
    int y0 = (int)floorf(fy); float wy = fy - (float)y0;
    int x0 = (int)floorf(fx); float wx = fx - (float)x0;
    int y1 = min(y0 + 1, r - 1); y0 = max(y0, 0);
    int x1 = min(x0 + 1, r - 1); x0 = max(x0, 0);
    const float* p0 = rgb + (size_t)b * r * r;
    const float* p1 = rgb + (size_t)(BATCH + b) * r * r;
    float v00 = p0[y0 * r + x0] + p1[y0 * r + x0];
    float v01 = p0[y0 * r + x1] + p1[y0 * r + x1];
    float v10 = p0[y1 * r + x0] + p1[y1 * r + x0];
    float v11 = p0[y1 * r + x1] + p1[y1 * r + x1];
    float v = (1.f - wy) * ((1.f - wx) * v00 + wx * v01)
            +        wy  * ((1.f - wx) * v10 + wx * v11);
    int oidx = (b << 16) | (oy << 8) | ox;
    acc[oidx] = (beta ? acc[oidx] : 0.f) + v;
}

__global__ void k_final(float* __restrict__ out, int total) {
    int idx = blockIdx.x * blockDim.x + threadIdx.x;
    if (idx < total) out[idx] = out[idx] * 0.5f + 0.5f;
}

extern "C" void kernel_launch(void* const* d_in, const int* in_sizes, int n_in,
                              void* d_out, int out_size, void* d_ws, size_t ws_size,
                              hipStream_t stream) {
    const float* w     = (const float*)d_in[0];
    const float* noise[4] = {(const float*)d_in[1], (const float*)d_in[2],
                             (const float*)d_in[3], (const float*)d_in[4]};
    const float* ic    = (const float*)d_in[5];
    const float* tsw   = (const float*)d_in[6];
    const float* tsb   = (const float*)d_in[7];
    const float* cw    = (const float*)d_in[8];
    const float* snp   = (const float*)d_in[9];
    const float* sbias = (const float*)d_in[10];
    const float* rgbw  = (const float*)d_in[11];

    const size_t WM_BYTES = 8ull * 8 * 9 * 4 * 8 * 64 * 8 * 2; // 18,874,368
    const size_t RGBB = 2ull * BATCH * 65536 * 4;              // 4,194,304
    const size_t FIXED = 16384 + 32768 + RGBB + WM_BYTES;
    const size_t PER_S = 65536ull * 128 * 2;                   // 16,777,216
    int g = 0;
    for (int cand = 8; cand >= 1; cand >>= 1)
        if (ws_size >= FIXED + 2ull * cand * PER_S) { g = cand; break; }
    if (g == 0) return;

    char* ws = (char*)d_ws;
    float* s_all   = (float*)ws;
    float* d_all   = (float*)(ws + 16384);
    float* rgbb    = (float*)(ws + 49152);
    ushortT* wmall = (ushortT*)(ws + 49152 + RGBB);
    ushortT* bufA  = (ushortT*)(ws + FIXED);
    ushortT* bufB  = (ushortT*)(ws + FIXED + (size_t)g * PER_S);
    float* accb    = (float*)d_out;

    k_style<<<64, 64, 0, stream>>>(w, tsw, tsb, s_all);
    k_demod<<<1024, 64, 0, stream>>>(cw, s_all, d_all);
    k_wmodF<<<4608, 256, 0, stream>>>(cw, s_all, wmall);

    #define CONV(T2, SRC, DST, L, R, B0, G, RGB) do {                          \
        dim3 grid(((R) / 16) * ((R) / 8), (G));                                \
        k_conv7<T2><<<grid, 256, 0, stream>>>((SRC), (DST),                    \
            wmall + (size_t)(L) * (8 * 9 * 4 * 4096), d_all + (L) * BATCH * NF,\
            noise[(L) >> 1] + (size_t)((L) & 1) * BATCH * (R) * (R),           \
            sbias + (L) * NF, snp + (L), s_all + ((L) >> 1) * BATCH * NF,      \
            rgbw + ((L) >> 1) * NF, rgbb, (R), (R), (B0), (RGB));              \
    } while (0)

    if (g >= 2) {
        // ---- blocks 0..2 at full batch 8 ----
        ushortT* xb = bufA;
        ushortT* tb = bufB;
        k_prep_init<<<4096, 256, 0, stream>>>(ic, xb, BATCH * 1024 * 128);
        for (int i = 0; i < 3; ++i) {
            int r = 32 << i;
            if (i > 0) {
                int total = BATCH * r * r * 16;
                int blocks = (total + 255) / 256;
                if (blocks > 2048) blocks = 2048;
                k_up2_bf<<<blocks, 256, 0, stream>>>(xb, tb, r / 2, r / 2, total);
                ushortT* t2 = xb; xb = tb; tb = t2;
            }
            CONV(0, xb, tb, i * 2 + 0, r, 0, BATCH, 0);
            { ushortT* t2 = xb; xb = tb; tb = t2; }
            CONV(0, xb, tb, i * 2 + 1, r, 0, BATCH, 1);
            { ushortT* t2 = xb; xb = tb; tb = t2; }
            int tot = BATCH * 256 * 256;
            k_rgbacc<<<(tot + 255) / 256, 256, 0, stream>>>(rgbb, accb, r, i > 0, 0, BATCH);
        }
        // ---- block 3: per g-group {up2 -> mega}; x128 in xb, up256 in tb ----
        for (int b0 = 0; b0 < BATCH; b0 += g) {
            int total = g * 256 * 256 * 16;
            k_up2_bf<<<2048, 256, 0, stream>>>(xb + (size_t)b0 * 2097152, tb,
                                               128, 128, total);
            dim3 mgrid(512, g);
            k_mega<<<mgrid, 256, 0, stream>>>(tb,
                wmall + 6ull * (8 * 9 * 4 * 4096), wmall + 7ull * (8 * 9 * 4 * 4096),
                d_all + 6 * BATCH * NF, d_all + 7 * BATCH * NF,
                noise[3], noise[3] + (size_t)BATCH * 65536,
                sbias + 6 * NF, sbias + 7 * NF, snp + 6, snp + 7,
                s_all + 3 * BATCH * NF, rgbw + 3 * NF, rgbb, b0);
        }
        int tot = BATCH * 256 * 256;
        k_rgbacc<<<(tot + 255) / 256, 256, 0, stream>>>(rgbb, accb, 256, 1, 0, BATCH);
    } else {
        // ---- fallback g==1: per-sample pipeline ----
        for (int b0 = 0; b0 < BATCH; ++b0) {
            ushortT* xb = bufA;
            ushortT* tb = bufB;
            k_prep_init<<<1024, 256, 0, stream>>>(ic, xb, 1024 * 128);
            for (int i = 0; i < NB; ++i) {
                int r = 32 << i;
                if (i > 0) {
                    int total = r * r * 16;
                    int blocks = (total + 255) / 256;
                    if (blocks > 2048) blocks = 2048;
                    k_up2_bf<<<blocks, 256, 0, stream>>>(xb, tb, r / 2, r / 2, total);
                    ushortT* t2 = xb; xb = tb; tb = t2;
                }
                CONV(0, xb, tb, i * 2 + 0, r, b0, 1, 0);
                { ushortT* t2 = xb; xb = tb; tb = t2; }
                if (i < 3) {
                    CONV(0, xb, tb, i * 2 + 1, r, b0, 1, 1);
                    { ushortT* t2 = xb; xb = tb; tb = t2; }
                } else {
                    CONV(1, xb, tb, 7, r, b0, 1, 1);
                }
                int tot = 1 * 256 * 256;
                k_rgbacc<<<(tot + 255) / 256, 256, 0, stream>>>(rgbb, accb, r, i > 0, b0, 1);
            }
        }
    }
    #undef CONV
    k_final<<<(out_size + 255) / 256, 256, 0, stream>>>(accb, out_size);
}

// Round 17
// 769.041 us; speedup vs baseline: 1.3561x; 1.1961x over previous
//
#include <hip/hip_runtime.h>
#include <math.h>

#define NB 4
#define BATCH 8
#define NF 128
#define WDIM 512
#define EPS_D 1e-8f

typedef unsigned short ushortT;
typedef __attribute__((ext_vector_type(8))) short short8v;
typedef __attribute__((ext_vector_type(8))) unsigned short ushort8v;
typedef __attribute__((ext_vector_type(4))) float float4v;
typedef __attribute__((ext_vector_type(4))) unsigned int uint4v;
typedef __attribute__((ext_vector_type(2))) unsigned int uint2v;

__device__ inline unsigned short f2bf(float f) {
    unsigned u = __builtin_bit_cast(unsigned, f);
    u = (u + 0x7fffu + ((u >> 16) & 1u)) >> 16;
    return (unsigned short)u;
}
__device__ inline float bf2f(unsigned short h) {
    unsigned u = ((unsigned)h) << 16;
    return __builtin_bit_cast(float, u);
}

// ---------------- style
__global__ void k_style(const float* __restrict__ w,
                        const float* __restrict__ tsw,
                        const float* __restrict__ tsb,
                        float* __restrict__ s) {
    int gid = blockIdx.x * blockDim.x + threadIdx.x;
    if (gid >= NB * BATCH * NF) return;
    int i = gid >> 10;
    int b = (gid >> 7) & 7;
    int o = gid & 127;
    const float cl = 0.044194173824159216f; // 1/sqrt(512)
    const float* wr = w + (i * BATCH + b) * WDIM;
    const float* tr = tsw + (i * NF + o) * WDIM;
    float acc = 0.f;
    for (int k = 0; k < WDIM; ++k) acc += wr[k] * tr[k];
    s[gid] = acc * cl + tsb[i * NF + o];
}

// ---------------- demod (f32 exact)
__global__ void k_demod(const float* __restrict__ conv_w,
                        const float* __restrict__ s,
                        float* __restrict__ d) {
    int bx = blockIdx.x; // l*128 + o
    int l = bx >> 7;
    int o = bx & 127;
    int lane = threadIdx.x;
    const float* wb = conv_w + (size_t)((l * NF + o) * NF) * 9;
    float t0 = 0.f, t1 = 0.f;
    for (int k = 0; k < 9; ++k) {
        float a = wb[lane * 9 + k];        t0 += a * a;
        float c = wb[(lane + 64) * 9 + k]; t1 += c * c;
    }
    const float c2 = 1.0f / 1152.0f;
    int i = l >> 1;
    for (int b = 0; b < BATCH; ++b) {
        float s0 = s[(i * BATCH + b) * NF + lane];
        float s1 = s[(i * BATCH + b) * NF + lane + 64];
        float v = t0 * s0 * s0 + t1 * s1 * s1;
        for (int off = 32; off > 0; off >>= 1) v += __shfl_down(v, off);
        if (lane == 0) d[(l * BATCH + b) * NF + o] = rsqrtf(v * c2 + EPS_D);
    }
}

// ---------------- fragment-major modulated weights
__global__ void k_wmodF(const float* __restrict__ cw, const float* __restrict__ s,
                        ushortT* __restrict__ wm) {
    int idx = blockIdx.x * blockDim.x + threadIdx.x; // 1,179,648
    int lane = idx & 63;
    int mf = (idx >> 6) & 7;
    int kcc = (idx >> 9) & 3;
    int t = (idx >> 11) % 9;
    int r2 = idx / (2048 * 9);
    int b = r2 & 7;
    int l = r2 >> 3;
    if (l >= 8) return;
    const float cscale = 0.029462782549439483f; // 1/sqrt(1152)
    int co = mf * 16 + (lane & 15);
    int kb = kcc * 32 + (lane >> 4) * 8;
    const float* src = cw + (((size_t)l * NF + co) * NF) * 9;
    const float* sr = s + ((l >> 1) * BATCH + b) * NF;
    ushort8v o;
    #pragma unroll
    for (int e = 0; e < 8; ++e) {
        int ci = kb + e;
        o[e] = f2bf(src[(size_t)ci * 9 + t] * cscale * sr[ci]);
    }
    *(ushort8v*)(wm + (size_t)idx * 8) = o;
}

// ---------------- initial constant -> relu -> bf16 NHWC
__global__ void k_prep_init(const float* __restrict__ ic, ushortT* __restrict__ xp,
                            int total) {
    for (int idx = blockIdx.x * blockDim.x + threadIdx.x; idx < total;
         idx += gridDim.x * blockDim.x) {
        int ci = idx & 127;
        int p = (idx >> 7) & 1023;
        float v = ic[ci * 1024 + p];
        xp[idx] = f2bf(v > 0.f ? v : 0.f);
    }
}

// ---------------- 2x bilinear upsample, bf16 NHWC
__global__ void k_up2_bf(const ushortT* __restrict__ in, ushortT* __restrict__ out,
                         int h, int w, int total) {
    int W2 = w * 2, H2 = h * 2;
    for (int gid = blockIdx.x * blockDim.x + threadIdx.x; gid < total;
         gid += gridDim.x * blockDim.x) {
        int cg = gid & 15;
        int t = gid >> 4;
        int ox = t % W2; t /= W2;
        int oy = t % H2; int zb = t / H2;
        int y0 = (oy >> 1) - 1 + (oy & 1);
        float wy0 = (oy & 1) ? 0.75f : 0.25f;
        int x0 = (ox >> 1) - 1 + (ox & 1);
        float wx0 = (ox & 1) ? 0.75f : 0.25f;
        int y1 = min(y0 + 1, h - 1); y0 = max(y0, 0);
        int x1 = min(x0 + 1, w - 1); x0 = max(x0, 0);
        const ushortT* base = in + (size_t)zb * h * w * 128 + cg * 8;
        ushort8v v00 = *(const ushort8v*)(base + (size_t)(y0 * w + x0) * 128);
        ushort8v v01 = *(const ushort8v*)(base + (size_t)(y0 * w + x1) * 128);
        ushort8v v10 = *(const ushort8v*)(base + (size_t)(y1 * w + x0) * 128);
        ushort8v v11 = *(const ushort8v*)(base + (size_t)(y1 * w + x1) * 128);
        float wy1 = 1.f - wy0, wx1 = 1.f - wx0;
        ushort8v o;
        #pragma unroll
        for (int k = 0; k < 8; ++k) {
            float v = wy0 * (wx0 * bf2f(v00[k]) + wx1 * bf2f(v01[k]))
                    + wy1 * (wx0 * bf2f(v10[k]) + wx1 * bf2f(v11[k]));
            o[k] = f2bf(v);
        }
        *(ushort8v*)(out + ((size_t)(zb * H2 + oy) * W2 + ox) * 128 + cg * 8) = o;
    }
}

// ============ conv for r<=128 tiers (R8/R10-verified structure)
template<int NOY>
__global__ __launch_bounds__(256, 3) void k_conv7(
    const ushortT* __restrict__ xp, ushortT* __restrict__ yp,
    const ushortT* __restrict__ wF, const float* __restrict__ d_b,
    const float* __restrict__ nz, const float* __restrict__ bias,
    const float* __restrict__ sn_ptr, const float* __restrict__ s_blk,
    const float* __restrict__ rgbw_i, float* __restrict__ rgbb,
    int H, int W, int b0, int do_rgb)
{
    __shared__ __align__(16) char lb[46080];
    int tid = threadIdx.x;
    int lane = tid & 63;
    int wv = tid >> 6;
    int wm = wv & 1, wn = wv >> 1;
    int lm = lane & 15, lk = lane >> 4;
    int tilesX = W >> 4;
    int tx0 = (blockIdx.x % tilesX) << 4;
    int ty0 = (blockIdx.x / tilesX) << 3;
    int zb = blockIdx.y;
    int b = b0 + zb;

    const char* xbase = (const char*)(xp + (size_t)zb * H * W * 128);
    int offs[6];
    #pragma unroll
    for (int it = 0; it < 6; ++it) {
        int cw = it * 64 + lane;
        int off = -1;
        if (cw < 360) {
            int chunk = wv * 360 + cw;
            int px = chunk >> 3, slot = chunk & 7;
            int hy = px / 18, hx = px - hy * 18;
            int gy = ty0 + hy - 1, gx = tx0 + hx - 1;
            if ((unsigned)gy < (unsigned)H && (unsigned)gx < (unsigned)W)
                off = (gy * W + gx) * 256 + ((slot ^ (px & 7)) << 4);
        }
        offs[it] = off;
    }
    {
        const uint4v zv = {0, 0, 0, 0};
        #pragma unroll
        for (int c = 0; c < 12; ++c) {
            int idx = tid + c * 256;
            if (idx < 2880) *(uint4v*)(lb + idx * 16) = zv;
        }
    }
    __syncthreads();
    #pragma unroll
    for (int it = 0; it < 6; ++it)
        if (offs[it] >= 0)
            __builtin_amdgcn_global_load_lds(
                (const __attribute__((address_space(1))) void*)(xbase + offs[it]),
                (__attribute__((address_space(3))) void*)(lb + wv * 5760 + it * 1024), 16, 0, 0);
    __syncthreads();
    #pragma unroll
    for (int it = 0; it < 6; ++it)
        if (offs[it] >= 0)
            __builtin_amdgcn_global_load_lds(
                (const __attribute__((address_space(1))) void*)(xbase + offs[it] + 128),
                (__attribute__((address_space(3))) void*)(lb + 23040 + wv * 5760 + it * 1024), 16, 0, 0);

    float4v acc[4][4];
    #pragma unroll
    for (int mf = 0; mf < 4; ++mf)
        #pragma unroll
        for (int nf = 0; nf < 4; ++nf)
            acc[mf][nf] = (float4v){0.f, 0.f, 0.f, 0.f};

    const ushortT* wB = wF + (size_t)b * (9 * 4 * 4096);
    for (int cih = 0; cih < 2; ++cih) {
        if (cih) __syncthreads();
        const char* buf = lb + cih * 23040;
        #pragma unroll
        for (int tap = 0; tap < 9; ++tap) {
            const int dy = (tap < 3) ? 0 : (tap < 6 ? 1 : 2);
            const int dx = tap - dy * 3;
            #pragma unroll
            for (int kc = 0; kc < 2; ++kc) {
                const ushortT* ap = wB + ((size_t)(tap * 4 + cih * 2 + kc) << 12)
                                    + wm * 2048 + lane * 8;
                short8v a0 = *(const short8v*)(ap);
                short8v a1 = *(const short8v*)(ap + 512);
                short8v a2 = *(const short8v*)(ap + 1024);
                short8v a3 = *(const short8v*)(ap + 1536);
                #pragma unroll
                for (int nf = 0; nf < 4; ++nf) {
                    int row = nf * 2 + (lm >> 3) + dy;
                    int col = wn * 8 + (lm & 7) + dx;
                    int hp = row * 18 + col;
                    short8v bf = *(const short8v*)(buf + hp * 128
                                 + ((((kc << 2) + lk) ^ (hp & 7)) << 4));
                    acc[0][nf] = __builtin_amdgcn_mfma_f32_16x16x32_bf16(a0, bf, acc[0][nf], 0, 0, 0);
                    acc[1][nf] = __builtin_amdgcn_mfma_f32_16x16x32_bf16(a1, bf, acc[1][nf], 0, 0, 0);
                    acc[2][nf] = __builtin_amdgcn_mfma_f32_16x16x32_bf16(a2, bf, acc[2][nf], 0, 0, 0);
                    acc[3][nf] = __builtin_amdgcn_mfma_f32_16x16x32_bf16(a3, bf, acc[3][nf], 0, 0, 0);
                }
            }
        }
    }
    __syncthreads();

    float sn = sn_ptr[0];
    float nv[4];
    #pragma unroll
    for (int nf = 0; nf < 4; ++nf) {
        int gy = ty0 + nf * 2 + (lm >> 3);
        int gx = tx0 + wn * 8 + (lm & 7);
        nv[nf] = sn * nz[((size_t)b * H + gy) * W + gx];
    }
    const float cl2 = 0.08838834764831845f;

    if (NOY) {
        float rgbs[4] = {0.f, 0.f, 0.f, 0.f};
        #pragma unroll
        for (int mf = 0; mf < 4; ++mf) {
            int co0 = wm * 64 + mf * 16 + lk * 4;
            float4v dd = *(const float4v*)(d_b + b * 128 + co0);
            float4v bb = *(const float4v*)(bias + co0);
            float4v rw = *(const float4v*)(rgbw_i + co0);
            float4v sv = *(const float4v*)(s_blk + b * 128 + co0);
            #pragma unroll
            for (int nf = 0; nf < 4; ++nf)
                #pragma unroll
                for (int e = 0; e < 4; ++e) {
                    float t = acc[mf][nf][e] * dd[e] + nv[nf] + bb[e];
                    t = t > 0.f ? t : 0.2f * t;
                    rgbs[nf] += t * rw[e] * cl2 * sv[e];
                }
        }
        #pragma unroll
        for (int nf = 0; nf < 4; ++nf) {
            float r = rgbs[nf];
            r += __shfl_xor(r, 16, 64);
            r += __shfl_xor(r, 32, 64);
            if (lane < 16) {
                int gy = ty0 + nf * 2 + (lane >> 3);
                int gx = tx0 + wn * 8 + (lane & 7);
                rgbb[((size_t)(wm * BATCH + b) * H + gy) * W + gx] = r;
            }
        }
        return;
    }

    float rgbs[4] = {0.f, 0.f, 0.f, 0.f};
    unsigned pka[4][4][2];
    #pragma unroll
    for (int mf = 0; mf < 4; ++mf) {
        int co0 = wm * 64 + mf * 16 + lk * 4;
        float4v dd = *(const float4v*)(d_b + b * 128 + co0);
        float4v bb = *(const float4v*)(bias + co0);
        float4v cf = {0.f, 0.f, 0.f, 0.f};
        if (do_rgb) {
            float4v rw = *(const float4v*)(rgbw_i + co0);
            float4v sv = *(const float4v*)(s_blk + b * 128 + co0);
            #pragma unroll
            for (int e = 0; e < 4; ++e) cf[e] = rw[e] * cl2 * sv[e];
        }
        #pragma unroll
        for (int nf = 0; nf < 4; ++nf) {
            float v[4];
            #pragma unroll
            for (int e = 0; e < 4; ++e) {
                float t = acc[mf][nf][e] * dd[e] + nv[nf] + bb[e];
                v[e] = t > 0.f ? t : 0.2f * t;
            }
            if (do_rgb)
                rgbs[nf] += v[0] * cf[0] + v[1] * cf[1] + v[2] * cf[2] + v[3] * cf[3];
            pka[mf][nf][0] = (unsigned)f2bf(v[0]) | ((unsigned)f2bf(v[1]) << 16);
            pka[mf][nf][1] = (unsigned)f2bf(v[2]) | ((unsigned)f2bf(v[3]) << 16);
        }
    }
    if (do_rgb) {
        #pragma unroll
        for (int nf = 0; nf < 4; ++nf) {
            float r = rgbs[nf];
            r += __shfl_xor(r, 16, 64);
            r += __shfl_xor(r, 32, 64);
            if (lane < 16) {
                int gy = ty0 + nf * 2 + (lane >> 3);
                int gx = tx0 + wn * 8 + (lane & 7);
                rgbb[((size_t)(wm * BATCH + b) * H + gy) * W + gx] = r;
            }
        }
    }
    char* xb2 = (char*)(yp + (size_t)zb * H * W * 128);
    #pragma unroll
    for (int h = 0; h < 2; ++h) {
        if (wm == h) {
            #pragma unroll
            for (int mf = 0; mf < 4; ++mf) {
                int cb = (mf * 16 + lk * 4) * 2;
                #pragma unroll
                for (int nf = 0; nf < 4; ++nf) {
                    int pxl = (nf * 2 + (lm >> 3)) * 16 + wn * 8 + (lm & 7);
                    int ad = pxl * 128 + (cb ^ ((pxl & 7) << 4));
                    uint2v pk2;
                    pk2[0] = pka[mf][nf][0];
                    pk2[1] = pka[mf][nf][1];
                    *(uint2v*)(lb + ad) = pk2;
                }
            }
        }
        __syncthreads();
        for (int c = tid; c < 1024; c += 256) {
            int pxl = c >> 3, ck = c & 7;
            uint4v v = *(const uint4v*)(lb + pxl * 128 + ((ck << 4) ^ ((pxl & 7) << 4)));
            int gy = ty0 + (pxl >> 4), gx = tx0 + (pxl & 15);
            *(uint4v*)(xb2 + ((size_t)(gy * W + gx)) * 256 + h * 128 + ck * 16) = v;
        }
        if (h == 0) __syncthreads();
    }
}

// ============ MEGA (R14-verified): block 3 fused conv(l6)+conv(l7)+ToRGB.
// Input = pre-materialized up256 (NHWC). Single-buffer quarter DMA with
// explicit vmcnt(0) drain + sched_barrier fences before every barrier.
__global__ __launch_bounds__(256, 2) void k_mega(
    const ushortT* __restrict__ up256,  // [g][256][256][128] bf16
    const ushortT* __restrict__ wm6, const ushortT* __restrict__ wm7,
    const float* __restrict__ d6, const float* __restrict__ d7,
    const float* __restrict__ nz6, const float* __restrict__ nz7,
    const float* __restrict__ bias6, const float* __restrict__ bias7,
    const float* __restrict__ sn6p, const float* __restrict__ sn7p,
    const float* __restrict__ s_blk, const float* __restrict__ rgbw_i,
    float* __restrict__ rgbb, int b0)
{
    __shared__ __align__(16) char lb[61440];  // [0,15360) quarter | [15360,61440) j0out
    const int J0 = 15360;
    int tid = threadIdx.x;
    int lane = tid & 63;
    int wv = tid >> 6;
    int wm = wv & 1, wn = wv >> 1;
    int lm = lane & 15, lk = lane >> 4;
    int tx0 = (blockIdx.x & 15) << 4;
    int ty0 = (blockIdx.x >> 4) << 3;
    int zb = blockIdx.y;
    int b = b0 + zb;

    int ib[6], prr[6], pcc[6];
    bool pv[6];
    #pragma unroll
    for (int nf = 0; nf < 6; ++nf) {
        int p = wn * 96 + nf * 16 + lm;
        pv[nf] = (p < 180);
        int pc = pv[nf] ? p : 0;
        prr[nf] = pc / 18;
        pcc[nf] = pc - prr[nf] * 18;
        ib[nf] = prr[nf] * 20 + pcc[nf];
    }

    const char* xbase = (const char*)(up256 + (size_t)zb * 256 * 256 * 128);
    int offs[4];
    #pragma unroll
    for (int k = 0; k < 4; ++k) {
        int c = tid + k * 256;
        int off = -1;
        if (c < 960) {
            int ip = c >> 2, d = c & 3;
            int iy = ip / 20, ix = ip - iy * 20;
            int oy = ty0 + iy - 2, ox = tx0 + ix - 2;
            if ((unsigned)oy < 256u && (unsigned)ox < 256u)
                off = (oy * 256 + ox) * 256 + ((d ^ ((ip >> 1) & 3)) << 4);
        }
        offs[k] = off;
    }
    {
        const uint4v zv = {0, 0, 0, 0};
        for (int c = tid; c < 960; c += 256) *(uint4v*)(lb + c * 16) = zv;
    }
    __syncthreads();

    float4v j0a[4][6];
    #pragma unroll
    for (int mf = 0; mf < 4; ++mf)
        #pragma unroll
        for (int nf = 0; nf < 6; ++nf)
            j0a[mf][nf] = (float4v){0.f, 0.f, 0.f, 0.f};

    const ushortT* wB6 = wm6 + (size_t)b * (9 * 4 * 4096);
    const ushortT* wB7 = wm7 + (size_t)b * (9 * 4 * 4096);

    for (int q = 0; q < 4; ++q) {
        // ---- DMA-stage input quarter q (fenced: no hoist, explicit drain) ----
        __builtin_amdgcn_sched_barrier(0);
        #pragma unroll
        for (int k = 0; k < 4; ++k)
            if (offs[k] >= 0)
                __builtin_amdgcn_global_load_lds(
                    (const __attribute__((address_space(1))) void*)(xbase + offs[k] + q * 64),
                    (__attribute__((address_space(3))) void*)(lb + k * 4096 + wv * 1024), 16, 0, 0);
        asm volatile("s_waitcnt vmcnt(0)" ::: "memory");
        __builtin_amdgcn_sched_barrier(0);
        __syncthreads();
        // ---- j0 MFMA over quarter q ----
        #pragma unroll
        for (int tap = 0; tap < 9; ++tap) {
            const int dy = (tap < 3) ? 0 : (tap < 6 ? 1 : 2);
            const int dx = tap - dy * 3;
            const ushortT* ap = wB6 + ((size_t)(tap * 4 + q) << 12) + wm * 2048 + lane * 8;
            short8v a0 = *(const short8v*)(ap);
            short8v a1 = *(const short8v*)(ap + 512);
            short8v a2 = *(const short8v*)(ap + 1024);
            short8v a3 = *(const short8v*)(ap + 1536);
            #pragma unroll
            for (int nf = 0; nf < 6; ++nf) {
                int ipx = ib[nf] + dy * 20 + dx;
                short8v bf = *(const short8v*)(lb + ipx * 64
                             + ((lk ^ ((ipx >> 1) & 3)) << 4));
                j0a[0][nf] = __builtin_amdgcn_mfma_f32_16x16x32_bf16(a0, bf, j0a[0][nf], 0, 0, 0);
                j0a[1][nf] = __builtin_amdgcn_mfma_f32_16x16x32_bf16(a1, bf, j0a[1][nf], 0, 0, 0);
                j0a[2][nf] = __builtin_amdgcn_mfma_f32_16x16x32_bf16(a2, bf, j0a[2][nf], 0, 0, 0);
                j0a[3][nf] = __builtin_amdgcn_mfma_f32_16x16x32_bf16(a3, bf, j0a[3][nf], 0, 0, 0);
            }
        }
        __builtin_amdgcn_sched_barrier(0);
        __syncthreads();
        __builtin_amdgcn_sched_barrier(0);
    }

    // ---- j0 epilogue -> j0out LDS (swizzled 256B/px, zero outside image) ----
    {
        float sn6 = sn6p[0];
        #pragma unroll
        for (int nf = 0; nf < 6; ++nf) {
            if (!pv[nf]) continue;
            int p = wn * 96 + nf * 16 + lm;
            int oy = ty0 + prr[nf] - 1, ox = tx0 + pcc[nf] - 1;
            bool inimg = ((unsigned)oy < 256u) && ((unsigned)ox < 256u);
            float nv = inimg ? sn6 * nz6[((size_t)b * 256 + oy) * 256 + ox] : 0.f;
            #pragma unroll
            for (int mf = 0; mf < 4; ++mf) {
                int co0 = wm * 64 + mf * 16 + lk * 4;
                uint2v pk2 = {0u, 0u};
                if (inimg) {
                    float4v dd = *(const float4v*)(d6 + b * 128 + co0);
                    float4v bb = *(const float4v*)(bias6 + co0);
                    float v[4];
                    #pragma unroll
                    for (int e = 0; e < 4; ++e) {
                        float t = j0a[mf][nf][e] * dd[e] + nv + bb[e];
                        v[e] = t > 0.f ? t : 0.2f * t;
                    }
                    pk2[0] = (unsigned)f2bf(v[0]) | ((unsigned)f2bf(v[1]) << 16);
                    pk2[1] = (unsigned)f2bf(v[2]) | ((unsigned)f2bf(v[3]) << 16);
                }
                int ad = p * 256 + ((co0 * 2) ^ ((p & 7) << 4));
                *(uint2v*)(lb + J0 + ad) = pk2;
            }
        }
    }
    __syncthreads();

    // ---- j1 conv (layer 7) reading j0out; fused ToRGB; no y store ----
    float4v acc[4][4];
    #pragma unroll
    for (int mf = 0; mf < 4; ++mf)
        #pragma unroll
        for (int nf = 0; nf < 4; ++nf)
            acc[mf][nf] = (float4v){0.f, 0.f, 0.f, 0.f};

    #pragma unroll
    for (int tap = 0; tap < 9; ++tap) {
        const int dy = (tap < 3) ? 0 : (tap < 6 ? 1 : 2);
        const int dx = tap - dy * 3;
        #pragma unroll
        for (int kcc = 0; kcc < 4; ++kcc) {
            const ushortT* ap = wB7 + ((size_t)(tap * 4 + kcc) << 12) + wm * 2048 + lane * 8;
            short8v a0 = *(const short8v*)(ap);
            short8v a1 = *(const short8v*)(ap + 512);
            short8v a2 = *(const short8v*)(ap + 1024);
            short8v a3 = *(const short8v*)(ap + 1536);
            #pragma unroll
            for (int nf = 0; nf < 4; ++nf) {
                int row = nf * 2 + (lm >> 3) + dy;
                int col = wn * 8 + (lm & 7) + dx;
                int hp = row * 18 + col;
                short8v bf = *(const short8v*)(lb + J0 + hp * 256
                             + ((kcc * 64 + lk * 16) ^ ((hp & 7) << 4)));
                acc[0][nf] = __builtin_amdgcn_mfma_f32_16x16x32_bf16(a0, bf, acc[0][nf], 0, 0, 0);
                acc[1][nf] = __builtin_amdgcn_mfma_f32_16x16x32_bf16(a1, bf, acc[1][nf], 0, 0, 0);
                acc[2][nf] = __builtin_amdgcn_mfma_f32_16x16x32_bf16(a2, bf, acc[2][nf], 0, 0, 0);
                acc[3][nf] = __builtin_amdgcn_mfma_f32_16x16x32_bf16(a3, bf, acc[3][nf], 0, 0, 0);
            }
        }
    }

    float sn7 = sn7p[0];
    float nv7[4];
    #pragma unroll
    for (int nf = 0; nf < 4; ++nf) {
        int gy = ty0 + nf * 2 + (lm >> 3);
        int gx = tx0 + wn * 8 + (lm & 7);
        nv7[nf] = sn7 * nz7[((size_t)b * 256 + gy) * 256 + gx];
    }
    const float cl2 = 0.08838834764831845f;
    float rgbs[4] = {0.f, 0.f, 0.f, 0.f};
    #pragma unroll
    for (int mf = 0; mf < 4; ++mf) {
        int co0 = wm * 64 + mf * 16 + lk * 4;
        float4v dd = *(const float4v*)(d7 + b * 128 + co0);
        float4v bb = *(const float4v*)(bias7 + co0);
        float4v rw = *(const float4v*)(rgbw_i + co0);
        float4v sv = *(const float4v*)(s_blk + b * 128 + co0);
        #pragma unroll
        for (int nf = 0; nf < 4; ++nf)
            #pragma unroll
            for (int e = 0; e < 4; ++e) {
                float t = acc[mf][nf][e] * dd[e] + nv7[nf] + bb[e];
                t = t > 0.f ? t : 0.2f * t;
                rgbs[nf] += t * rw[e] * cl2 * sv[e];
            }
    }
    #pragma unroll
    for (int nf = 0; nf < 4; ++nf) {
        float r = rgbs[nf];
        r += __shfl_xor(r, 16, 64);
        r += __shfl_xor(r, 32, 64);
        if (lane < 16) {
            int gy = ty0 + nf * 2 + (lane >> 3);
            int gx = tx0 + wn * 8 + (lane & 7);
            rgbb[((size_t)(wm * BATCH + b) * 256 + gy) * 256 + gx] = r;
        }
    }
}

// ---------------- bilinear upsample rgb (r->256), sum 2 partial planes
__global__ void k_rgbacc(const float* __restrict__ rgb, float* __restrict__ acc,
                         int r, int beta, int b0, int g) {
    int idx = blockIdx.x * blockDim.x + threadIdx.x;
    if (idx >= g * 256 * 256) return;
    int ox = idx & 255;
    int oy = (idx >> 8) & 255;
    int b = b0 + (idx >> 16);
    float scale = (float)r * (1.0f / 256.0f);
    float fy = (oy + 0.5f) * scale - 0.5f;
    float fx = (ox + 0.5f) * scale - 0.5f;
    int y0 = (int)floorf(fy); float wy = fy - (float)y0;
    int x0 = (int)floorf(fx); float wx = fx - (float)x0;
    int y1 = min(y0 + 1, r - 1); y0 = max(y0, 0);
    int x1 = min(x0 + 1, r - 1); x0 = max(x0, 0);
    const float* p0 = rgb + (size_t)b * r * r;
    const float* p1 = rgb + (size_t)(BATCH + b) * r * r;
    float v00 = p0[y0 * r + x0] + p1[y0 * r + x0];
    float v01 = p0[y0 * r + x1] + p1[y0 * r + x1];
    float v10 = p0[y1 * r + x0] + p1[y1 * r + x0];
    float v11 = p0[y1 * r + x1] + p1[y1 * r + x1];
    float v = (1.f - wy) * ((1.f - wx) * v00 + wx * v01)
            +        wy  * ((1.f - wx) * v10 + wx * v11);
    int oidx = (b << 16) | (oy << 8) | ox;
    acc[oidx] = (beta ? acc[oidx] : 0.f) + v;
}

__global__ void k_final(float* __restrict__ out, int total) {
    int idx = blockIdx.x * blockDim.x + threadIdx.x;
    if (idx < total) out[idx] = out[idx] * 0.5f + 0.5f;
}

extern "C" void kernel_launch(void* const* d_in, const int* in_sizes, int n_in,
                              void* d_out, int out_size, void* d_ws, size_t ws_size,
                              hipStream_t stream) {
    const float* w     = (const float*)d_in[0];
    const float* noise[4] = {(const float*)d_in[1], (const float*)d_in[2],
                             (const float*)d_in[3], (const float*)d_in[4]};
    const float* ic    = (const float*)d_in[5];
    const float* tsw   = (const float*)d_in[6];
    const float* tsb   = (const float*)d_in[7];
    const float* cw    = (const float*)d_in[8];
    const float* snp   = (const float*)d_in[9];
    const float* sbias = (const float*)d_in[10];
    const float* rgbw  = (const float*)d_in[11];

    const size_t WM_BYTES = 8ull * 8 * 9 * 4 * 8 * 64 * 8 * 2; // 18,874,368
    const size_t RGBB = 2ull * BATCH * 65536 * 4;              // 4,194,304
    const size_t FIXED = 16384 + 32768 + RGBB + WM_BYTES;
    const size_t PER_S = 65536ull * 128 * 2;                   // 16,777,216
    int g = 0;
    for (int cand = 8; cand >= 1; cand >>= 1)
        if (ws_size >= FIXED + 2ull * cand * PER_S) { g = cand; break; }
    if (g == 0) return;

    char* ws = (char*)d_ws;
    float* s_all   = (float*)ws;
    float* d_all   = (float*)(ws + 16384);
    float* rgbb    = (float*)(ws + 49152);
    ushortT* wmall = (ushortT*)(ws + 49152 + RGBB);
    ushortT* bufA  = (ushortT*)(ws + FIXED);
    ushortT* bufB  = (ushortT*)(ws + FIXED + (size_t)g * PER_S);
    float* accb    = (float*)d_out;

    k_style<<<64, 64, 0, stream>>>(w, tsw, tsb, s_all);
    k_demod<<<1024, 64, 0, stream>>>(cw, s_all, d_all);
    k_wmodF<<<4608, 256, 0, stream>>>(cw, s_all, wmall);

    #define CONV(T2, SRC, DST, L, R, B0, G, RGB) do {                          \
        dim3 grid(((R) / 16) * ((R) / 8), (G));                                \
        k_conv7<T2><<<grid, 256, 0, stream>>>((SRC), (DST),                    \
            wmall + (size_t)(L) * (8 * 9 * 4 * 4096), d_all + (L) * BATCH * NF,\
            noise[(L) >> 1] + (size_t)((L) & 1) * BATCH * (R) * (R),           \
            sbias + (L) * NF, snp + (L), s_all + ((L) >> 1) * BATCH * NF,      \
            rgbw + ((L) >> 1) * NF, rgbb, (R), (R), (B0), (RGB));              \
    } while (0)

    if (g >= 2) {
        // ---- blocks 0..2 at full batch 8 ----
        ushortT* xb = bufA;
        ushortT* tb = bufB;
        k_prep_init<<<4096, 256, 0, stream>>>(ic, xb, BATCH * 1024 * 128);
        for (int i = 0; i < 3; ++i) {
            int r = 32 << i;
            if (i > 0) {
                int total = BATCH * r * r * 16;
                int blocks = (total + 255) / 256;
                if (blocks > 2048) blocks = 2048;
                k_up2_bf<<<blocks, 256, 0, stream>>>(xb, tb, r / 2, r / 2, total);
                ushortT* t2 = xb; xb = tb; tb = t2;
            }
            CONV(0, xb, tb, i * 2 + 0, r, 0, BATCH, 0);
            { ushortT* t2 = xb; xb = tb; tb = t2; }
            CONV(0, xb, tb, i * 2 + 1, r, 0, BATCH, 1);
            { ushortT* t2 = xb; xb = tb; tb = t2; }
            int tot = BATCH * 256 * 256;
            k_rgbacc<<<(tot + 255) / 256, 256, 0, stream>>>(rgbb, accb, r, i > 0, 0, BATCH);
        }
        // ---- block 3: per g-group {up2 -> mega}; x128 in xb, up256 in tb ----
        for (int b0 = 0; b0 < BATCH; b0 += g) {
            int total = g * 256 * 256 * 16;
            k_up2_bf<<<2048, 256, 0, stream>>>(xb + (size_t)b0 * 2097152, tb,
                                               128, 128, total);
            dim3 mgrid(512, g);
            k_mega<<<mgrid, 256, 0, stream>>>(tb,
                wmall + 6ull * (8 * 9 * 4 * 4096), wmall + 7ull * (8 * 9 * 4 * 4096),
                d_all + 6 * BATCH * NF, d_all + 7 * BATCH * NF,
                noise[3], noise[3] + (size_t)BATCH * 65536,
                sbias + 6 * NF, sbias + 7 * NF, snp + 6, snp + 7,
                s_all + 3 * BATCH * NF, rgbw + 3 * NF, rgbb, b0);
        }
        int tot = BATCH * 256 * 256;
        k_rgbacc<<<(tot + 255) / 256, 256, 0, stream>>>(rgbb, accb, 256, 1, 0, BATCH);
    } else {
        // ---- fallback g==1: per-sample pipeline ----
        for (int b0 = 0; b0 < BATCH; ++b0) {
            ushortT* xb = bufA;
            ushortT* tb = bufB;
            k_prep_init<<<1024, 256, 0, stream>>>(ic, xb, 1024 * 128);
            for (int i = 0; i < NB; ++i) {
                int r = 32 << i;
                if (i > 0) {
                    int total = r * r * 16;
                    int blocks = (total + 255) / 256;
                    if (blocks > 2048) blocks = 2048;
                    k_up2_bf<<<blocks, 256, 0, stream>>>(xb, tb, r / 2, r / 2, total);
                    ushortT* t2 = xb; xb = tb; tb = t2;
                }
                CONV(0, xb, tb, i * 2 + 0, r, b0, 1, 0);
                { ushortT* t2 = xb; xb = tb; tb = t2; }
                if (i < 3) {
                    CONV(0, xb, tb, i * 2 + 1, r, b0, 1, 1);
                    { ushortT* t2 = xb; xb = tb; tb = t2; }
                } else {
                    CONV(1, xb, tb, 7, r, b0, 1, 1);
                }
                int tot = 1 * 256 * 256;
                k_rgbacc<<<(tot + 255) / 256, 256, 0, stream>>>(rgbb, accb, r, i > 0, b0, 1);
            }
        }
    }
    #undef CONV
    k_final<<<(out_size + 255) / 256, 256, 0, stream>>>(accb, out_size);
}